// Round 1
// baseline (209.444 us; speedup 1.0000x reference)
//
#include <hip/hip_runtime.h>
#include <math.h>

constexpr int B = 4;
constexpr int N = 16384;
constexpr int D = 256;
constexpr int M = 64;
constexpr int H = 8;
// HD = 32, 3D = 768

typedef __attribute__((ext_vector_type(8))) short short8;
typedef __attribute__((ext_vector_type(4))) float floatx4;

__device__ __forceinline__ float4 ld4(const float* p) {
  return *reinterpret_cast<const float4*>(p);
}
__device__ __forceinline__ unsigned short f2bf(float f) {
  unsigned u = __float_as_uint(f);
  unsigned r = (u + 0x7fffu + ((u >> 16) & 1u)) >> 16;  // RNE
  return (unsigned short)r;
}

// ---------------------------------------------------------------------------
// K0: one-time fp32 -> bf16 conversion of Ws (64x256), Wqkv (768x256),
// Wo (256x256). 34816 groups of 8 floats; grid 136 x 256 covers exactly.
__global__ __launch_bounds__(256) void k0_prep(
    const float* __restrict__ Ws, const float* __restrict__ Wqkv,
    const float* __restrict__ Wo, unsigned short* __restrict__ WsB,
    unsigned short* __restrict__ WqkvB, unsigned short* __restrict__ WoB) {
  const int g = blockIdx.x * 256 + threadIdx.x;
  const float* src;
  unsigned short* dst;
  int off;
  if (g < 2048) {
    src = Ws; dst = WsB; off = g;
  } else if (g < 26624) {
    src = Wqkv; dst = WqkvB; off = g - 2048;
  } else {
    src = Wo; dst = WoB; off = g - 26624;
  }
  const float4 a = ld4(&src[(size_t)off * 8]);
  const float4 c = ld4(&src[(size_t)off * 8 + 4]);
  unsigned d0 = (unsigned)f2bf(a.x) | ((unsigned)f2bf(a.y) << 16);
  unsigned d1 = (unsigned)f2bf(a.z) | ((unsigned)f2bf(a.w) << 16);
  unsigned d2 = (unsigned)f2bf(c.x) | ((unsigned)f2bf(c.y) << 16);
  unsigned d3 = (unsigned)f2bf(c.z) | ((unsigned)f2bf(c.w) << 16);
  *reinterpret_cast<uint4*>(&dst[(size_t)off * 8]) = make_uint4(d0, d1, d2, d3);
}

// ---------------------------------------------------------------------------
// K1 (fused): reads x fp32 directly. Per 64-n tile:
//   - stage x -> Xt bf16 [n][d]; Ws B-frags come straight from WsB (bf16,
//     L1/L2-resident) -> no Wt staging, LDS 77KB -> 43KB, 3 blocks/CU.
//   - MFMA logits GEMM, exp epilogue -> Es
//   - emit xbT[b,d,n] bf16, En[b,n,m], Et[b,m,n]; denom[b,m] atomics
// grid (N/64, B), block 256 (4 waves)
__global__ __launch_bounds__(256, 3) void k1_fused(
    const float* __restrict__ x, const unsigned short* __restrict__ WsB,
    const float* __restrict__ bs, unsigned short* __restrict__ xbT,
    unsigned short* __restrict__ En, unsigned short* __restrict__ Et,
    float* __restrict__ denom) {
  __shared__ unsigned short Xt[64][264];  // x tile [n][d] bf16
  __shared__ unsigned short Es[64][72];   // E tile [n][m] bf16
  __shared__ float red[64];
  const int b = blockIdx.y;
  const int n0 = blockIdx.x * 64;
  const int tid = threadIdx.x;
  const int w = tid >> 6, l = tid & 63;

  // stage: 64x256 fp32 -> bf16 (x only)
#pragma unroll
  for (int p = 0; p < 16; ++p) {
    const int i = p * 256 + tid;
    const int row = i >> 6;          // 0..63
    const int c4 = (i & 63) * 4;     // 0..252
    float4 v = ld4(&x[((size_t)(b * N + n0 + row)) * D + c4]);
    unsigned u0 = (unsigned)f2bf(v.x) | ((unsigned)f2bf(v.y) << 16);
    unsigned u1 = (unsigned)f2bf(v.z) | ((unsigned)f2bf(v.w) << 16);
    *reinterpret_cast<uint2*>(&Xt[row][c4]) = make_uint2(u0, u1);
  }
  if (tid < 64) red[tid] = 0.0f;
  __syncthreads();

  // MFMA logits GEMM: C[n, m] = sum_d x[n,d] * Ws[m,d]
  floatx4 acc[4] = {{0.f, 0.f, 0.f, 0.f},
                    {0.f, 0.f, 0.f, 0.f},
                    {0.f, 0.f, 0.f, 0.f},
                    {0.f, 0.f, 0.f, 0.f}};
  const int ar = w * 16 + (l & 15);
  const int q8 = (l >> 4) * 8;
#pragma unroll
  for (int ks = 0; ks < 8; ++ks) {
    short8 a = *reinterpret_cast<short8*>(&Xt[ar][ks * 32 + q8]);
#pragma unroll
    for (int mt = 0; mt < 4; ++mt) {
      short8 bf = *reinterpret_cast<const short8*>(
          &WsB[(size_t)(mt * 16 + (l & 15)) * 256 + ks * 32 + q8]);
      acc[mt] = __builtin_amdgcn_mfma_f32_16x16x32_bf16(a, bf, acc[mt], 0, 0, 0);
    }
  }

  // xbT emit: thread tid owns d-row = tid; column-read Xt (lane-adjacent u16
  // reads share dwords -> <=2-way, free), pack, 16B stores to own 128B row.
  {
    const int t = tid;
#pragma unroll
    for (int g = 0; g < 4; ++g) {
      unsigned dw[8];
#pragma unroll
      for (int j = 0; j < 8; ++j) {
        const unsigned lo = Xt[g * 16 + 2 * j][t];
        const unsigned hi = Xt[g * 16 + 2 * j + 1][t];
        dw[j] = lo | (hi << 16);
      }
      const size_t base = ((size_t)(b * D + t)) * N + n0 + g * 16;
      *reinterpret_cast<uint4*>(&xbT[base]) =
          make_uint4(dw[0], dw[1], dw[2], dw[3]);
      *reinterpret_cast<uint4*>(&xbT[base + 8]) =
          make_uint4(dw[4], dw[5], dw[6], dw[7]);
    }
  }

  // epilogue: exp + Es + denom partials
#pragma unroll
  for (int mt = 0; mt < 4; ++mt) {
    const int m = mt * 16 + (l & 15);
    const float bsm = bs[m];
    float s = 0.0f;
#pragma unroll
    for (int r = 0; r < 4; ++r) {
      const int n = w * 16 + (l >> 4) * 4 + r;
      const float e = expf(acc[mt][r] + bsm);
      s += e;
      Es[n][m] = f2bf(e);
    }
    atomicAdd(&red[m], s);
  }
  __syncthreads();
  if (tid < 64) atomicAdd(&denom[b * M + tid], red[tid]);
  // En writes (row-major, coalesced b128)
#pragma unroll
  for (int p = 0; p < 2; ++p) {
    const int g = p * 256 + tid;
    const int n = g >> 3;
    const int m0 = (g & 7) * 8;
    short8 v = *reinterpret_cast<short8*>(&Es[n][m0]);
    *reinterpret_cast<short8*>(&En[((size_t)(b * N + n0 + n)) * M + m0]) = v;
  }
  // Et writes (transposed)
#pragma unroll
  for (int p = 0; p < 2; ++p) {
    const int g = p * 256 + tid;
    const int m = g >> 3;
    const int n8 = (g & 7) * 8;
    unsigned short bu[8];
#pragma unroll
    for (int k = 0; k < 8; ++k) bu[k] = Es[n8 + k][m];
    uint4 pk;
    pk.x = (unsigned)bu[0] | ((unsigned)bu[1] << 16);
    pk.y = (unsigned)bu[2] | ((unsigned)bu[3] << 16);
    pk.z = (unsigned)bu[4] | ((unsigned)bu[5] << 16);
    pk.w = (unsigned)bu[6] | ((unsigned)bu[7] << 16);
    *reinterpret_cast<uint4*>(&Et[((size_t)(b * M + m)) * N + n0 + n8]) = pk;
  }
}

// ---------------------------------------------------------------------------
// K2: tokens_raw[b,m,d] += sum_n Et[b,m,n] * xbT[b,d,n]   (split-K over N)
// grid (D/64, N/512, B), block 256
__global__ __launch_bounds__(256) void k2_pool(
    const unsigned short* __restrict__ Et, const unsigned short* __restrict__ xbT,
    float* __restrict__ tokens) {
  __shared__ unsigned short EtS[64][72];
  __shared__ unsigned short XtS[64][72];
  const int dt = blockIdx.x, nc = blockIdx.y, b = blockIdx.z;
  const int d0 = dt * 64;
  const int tid = threadIdx.x;
  const int w = tid >> 6, l = tid & 63;
  floatx4 acc[4] = {{0.f, 0.f, 0.f, 0.f},
                    {0.f, 0.f, 0.f, 0.f},
                    {0.f, 0.f, 0.f, 0.f},
                    {0.f, 0.f, 0.f, 0.f}};
  const int q8 = (l >> 4) * 8;
  for (int kc = 0; kc < 8; ++kc) {
    const int nb = nc * 512 + kc * 64;
    __syncthreads();
#pragma unroll
    for (int p = 0; p < 2; ++p) {
      const int g = p * 256 + tid;
      const int row = g >> 3;
      const int c8 = (g & 7) * 8;
      *reinterpret_cast<short8*>(&EtS[row][c8]) =
          *reinterpret_cast<const short8*>(
              &Et[((size_t)(b * M + row)) * N + nb + c8]);
      *reinterpret_cast<short8*>(&XtS[row][c8]) =
          *reinterpret_cast<const short8*>(
              &xbT[((size_t)(b * D + d0 + row)) * N + nb + c8]);
    }
    __syncthreads();
#pragma unroll
    for (int ks = 0; ks < 2; ++ks) {
      short8 a = *reinterpret_cast<short8*>(&EtS[w * 16 + (l & 15)][ks * 32 + q8]);
#pragma unroll
      for (int dtile = 0; dtile < 4; ++dtile) {
        short8 bf = *reinterpret_cast<short8*>(
            &XtS[dtile * 16 + (l & 15)][ks * 32 + q8]);
        acc[dtile] =
            __builtin_amdgcn_mfma_f32_16x16x32_bf16(a, bf, acc[dtile], 0, 0, 0);
      }
    }
  }
#pragma unroll
  for (int dtile = 0; dtile < 4; ++dtile)
#pragma unroll
    for (int r = 0; r < 4; ++r) {
      const int m = w * 16 + (l >> 4) * 4 + r;
      const int d = d0 + dtile * 16 + (l & 15);
      atomicAdd(&tokens[((size_t)(b * M + m)) * D + d], acc[dtile][r]);
    }
}

// ---------------------------------------------------------------------------
// K_TOKENS: fused token stage. One block per batch b, 8 waves = 8 heads.
//   GEMM1: qkv[m, 96 cols of head w] = Tt x WqkvB^T, /denom -> q,k,vT in LDS
//   attn:  S = qk^T*scale (MFMA K=32), softmax (16-lane shfl), PV (MFMA)
//   GEMM2: out_tok = Ao x WoB^T + bo, /denom -> transposed bf16 TpT[b,d,m]
// LDS phases (116.25 KB peak):
//   A: Tt [64][264] bf16 @0 (33792) + denomS @118784
//   B: per-wave w*14848: qh[64][40], kh[64][40], vT[32][72]; P[64][72] over qh+kh
//   C: Ao [64][264] @0 ; D: Cs per-wave [64][34] bf16 @33792+w*4352
__global__ __launch_bounds__(512) void k_tokens(
    const float* __restrict__ tokens, const unsigned short* __restrict__ WqkvB,
    const unsigned short* __restrict__ WoB, const float* __restrict__ bo,
    const float* __restrict__ denom, unsigned short* __restrict__ TpT) {
  __shared__ __align__(16) char smem[119040];
  unsigned short* const Tt = reinterpret_cast<unsigned short*>(smem);  // [64][264]
  float* const denomS = reinterpret_cast<float*>(smem + 118784);       // [64]
  const int b = blockIdx.x;
  const int tid = threadIdx.x;
  const int w = tid >> 6;          // wave = head
  const int l = tid & 63;
  const int l15 = l & 15;
  const int q8 = (l >> 4) * 8;
  const int r4 = (l >> 4) * 4;

  // Phase A: stage tokens_raw fp32 -> Tt bf16
#pragma unroll
  for (int p = 0; p < 8; ++p) {
    const int i = p * 512 + tid;
    const int row = i >> 6;
    const int c4 = (i & 63) * 4;
    float4 v = ld4(&tokens[((size_t)(b * M + row)) * D + c4]);
    unsigned u0 = (unsigned)f2bf(v.x) | ((unsigned)f2bf(v.y) << 16);
    unsigned u1 = (unsigned)f2bf(v.z) | ((unsigned)f2bf(v.w) << 16);
    *reinterpret_cast<uint2*>(&Tt[row * 264 + c4]) = make_uint2(u0, u1);
  }
  if (tid < 64) denomS[tid] = denom[b * M + tid];
  __syncthreads();

  // GEMM1: head h = w; e-cols: et 0,1 -> q; 2,3 -> k; 4,5 -> v
  floatx4 acc[4][6];
#pragma unroll
  for (int mt = 0; mt < 4; ++mt)
#pragma unroll
    for (int et = 0; et < 6; ++et) acc[mt][et] = {0.f, 0.f, 0.f, 0.f};
#pragma unroll
  for (int ks = 0; ks < 8; ++ks) {
    short8 bfr[6];
#pragma unroll
    for (int et = 0; et < 6; ++et) {
      const int e = (et >> 1) * 256 + w * 32 + (et & 1) * 16 + l15;
      bfr[et] = *reinterpret_cast<const short8*>(
          &WqkvB[(size_t)e * 256 + ks * 32 + q8]);
    }
#pragma unroll
    for (int mt = 0; mt < 4; ++mt) {
      short8 a = *reinterpret_cast<const short8*>(
          &Tt[(mt * 16 + l15) * 264 + ks * 32 + q8]);
#pragma unroll
      for (int et = 0; et < 6; ++et)
        acc[mt][et] = __builtin_amdgcn_mfma_f32_16x16x32_bf16(a, bfr[et],
                                                              acc[mt][et], 0, 0, 0);
    }
  }

  float rcpd[4][4];
#pragma unroll
  for (int mt = 0; mt < 4; ++mt)
#pragma unroll
    for (int r = 0; r < 4; ++r) rcpd[mt][r] = 1.0f / denomS[mt * 16 + r4 + r];

  __syncthreads();  // all Tt reads done; overlay region now owned per-wave

  unsigned short* const qh = reinterpret_cast<unsigned short*>(smem + w * 14848);
  unsigned short* const kh = qh + 64 * 40;
  unsigned short* const vT = kh + 64 * 40;  // [32][72]
  unsigned short* const Pp = qh;            // [64][72] overlays qh+kh after scores

  // write q,k (normalized) row-major [m][hd]; v transposed [hd][m]
#pragma unroll
  for (int mt = 0; mt < 4; ++mt)
#pragma unroll
    for (int r = 0; r < 4; ++r) {
      const int m = mt * 16 + r4 + r;
      const float rc = rcpd[mt][r];
#pragma unroll
      for (int et = 0; et < 6; ++et) {
        const int c = (et & 1) * 16 + l15;
        const unsigned short bv = f2bf(acc[mt][et][r] * rc);
        if (et < 2) qh[m * 40 + c] = bv;
        else if (et < 4) kh[m * 40 + c] = bv;
        else vT[c * 72 + m] = bv;
      }
    }

  // scores: S[m][m'] = q . k, K=32 (one MFMA step)
  short8 qf[4], kf[4];
#pragma unroll
  for (int t = 0; t < 4; ++t) {
    qf[t] = *reinterpret_cast<const short8*>(&qh[(t * 16 + l15) * 40 + q8]);
    kf[t] = *reinterpret_cast<const short8*>(&kh[(t * 16 + l15) * 40 + q8]);
  }
  floatx4 sa[4][4];
#pragma unroll
  for (int it = 0; it < 4; ++it)
#pragma unroll
    for (int jt = 0; jt < 4; ++jt) sa[it][jt] = {0.f, 0.f, 0.f, 0.f};
#pragma unroll
  for (int it = 0; it < 4; ++it)
#pragma unroll
    for (int jt = 0; jt < 4; ++jt)
      sa[it][jt] =
          __builtin_amdgcn_mfma_f32_16x16x32_bf16(qf[it], kf[jt], sa[it][jt], 0, 0, 0);

  // softmax over m' (rows owned by 16-lane groups), write normalized P bf16
  constexpr float scale = 0.17677669529663687f;
#pragma unroll
  for (int it = 0; it < 4; ++it)
#pragma unroll
    for (int r = 0; r < 4; ++r) {
      float s0 = sa[it][0][r] * scale;
      float s1 = sa[it][1][r] * scale;
      float s2 = sa[it][2][r] * scale;
      float s3 = sa[it][3][r] * scale;
      float mx = fmaxf(fmaxf(s0, s1), fmaxf(s2, s3));
#pragma unroll
      for (int dd = 1; dd < 16; dd <<= 1) mx = fmaxf(mx, __shfl_xor(mx, dd));
      const float e0 = expf(s0 - mx), e1 = expf(s1 - mx);
      const float e2 = expf(s2 - mx), e3 = expf(s3 - mx);
      float sm = (e0 + e1) + (e2 + e3);
#pragma unroll
      for (int dd = 1; dd < 16; dd <<= 1) sm += __shfl_xor(sm, dd);
      const float ri = 1.0f / sm;
      const int m = it * 16 + r4 + r;
      Pp[m * 72 + l15] = f2bf(e0 * ri);
      Pp[m * 72 + 16 + l15] = f2bf(e1 * ri);
      Pp[m * 72 + 32 + l15] = f2bf(e2 * ri);
      Pp[m * 72 + 48 + l15] = f2bf(e3 * ri);
    }

  // PV: O[m][hd] = sum_m' P[m][m'] * vT[hd][m']
  floatx4 oa[4][2];
#pragma unroll
  for (int mt = 0; mt < 4; ++mt)
#pragma unroll
    for (int ht = 0; ht < 2; ++ht) oa[mt][ht] = {0.f, 0.f, 0.f, 0.f};
#pragma unroll
  for (int ks = 0; ks < 2; ++ks) {
    short8 pf[4], vf[2];
#pragma unroll
    for (int t = 0; t < 4; ++t)
      pf[t] = *reinterpret_cast<const short8*>(&Pp[(t * 16 + l15) * 72 + ks * 32 + q8]);
#pragma unroll
    for (int t = 0; t < 2; ++t)
      vf[t] = *reinterpret_cast<const short8*>(&vT[(t * 16 + l15) * 72 + ks * 32 + q8]);
#pragma unroll
    for (int mt = 0; mt < 4; ++mt)
#pragma unroll
      for (int ht = 0; ht < 2; ++ht)
        oa[mt][ht] =
            __builtin_amdgcn_mfma_f32_16x16x32_bf16(pf[mt], vf[ht], oa[mt][ht], 0, 0, 0);
  }
  __syncthreads();  // all waves done with per-wave bufs; Ao overlays

  unsigned short* const Ao = reinterpret_cast<unsigned short*>(smem);  // [64][264]
#pragma unroll
  for (int mt = 0; mt < 4; ++mt)
#pragma unroll
    for (int ht = 0; ht < 2; ++ht)
#pragma unroll
      for (int r = 0; r < 4; ++r)
        Ao[(mt * 16 + r4 + r) * 264 + w * 32 + ht * 16 + l15] = f2bf(oa[mt][ht][r]);
  __syncthreads();

  // GEMM2: out_tok[m][d] = Ao . Wo[d,:] ; wave w owns d-cols w*32..w*32+31
  floatx4 ca[4][2];
#pragma unroll
  for (int mt = 0; mt < 4; ++mt)
#pragma unroll
    for (int dt = 0; dt < 2; ++dt) ca[mt][dt] = {0.f, 0.f, 0.f, 0.f};
#pragma unroll
  for (int ks = 0; ks < 8; ++ks) {
    short8 bfr2[2];
#pragma unroll
    for (int dt = 0; dt < 2; ++dt)
      bfr2[dt] = *reinterpret_cast<const short8*>(
          &WoB[(size_t)(w * 32 + dt * 16 + l15) * 256 + ks * 32 + q8]);
#pragma unroll
    for (int mt = 0; mt < 4; ++mt) {
      short8 a = *reinterpret_cast<const short8*>(
          &Ao[(mt * 16 + l15) * 264 + ks * 32 + q8]);
#pragma unroll
      for (int dt = 0; dt < 2; ++dt)
        ca[mt][dt] =
            __builtin_amdgcn_mfma_f32_16x16x32_bf16(a, bfr2[dt], ca[mt][dt], 0, 0, 0);
    }
  }
  // epilogue: (+bias) * rcp(denom) -> Cs bf16, then transposed pack -> TpT
  unsigned short* const Cs =
      reinterpret_cast<unsigned short*>(smem + 33792 + w * 4352);  // [64][34]
#pragma unroll
  for (int mt = 0; mt < 4; ++mt)
#pragma unroll
    for (int r = 0; r < 4; ++r) {
      const int m = mt * 16 + r4 + r;
      const float rc = rcpd[mt][r];
#pragma unroll
      for (int dt = 0; dt < 2; ++dt) {
        const int dl = dt * 16 + l15;
        Cs[m * 34 + dl] = f2bf((ca[mt][dt][r] + bo[w * 32 + dl]) * rc);
      }
    }
  {
    const int dl = l & 31;
    const int m0 = (l >> 5) * 32;
    unsigned dwv[16];
#pragma unroll
    for (int k = 0; k < 16; ++k) {
      const unsigned lo = Cs[(m0 + 2 * k) * 34 + dl];
      const unsigned hi = Cs[(m0 + 2 * k + 1) * 34 + dl];
      dwv[k] = lo | (hi << 16);
    }
    const size_t gb = ((size_t)(b * D + w * 32 + dl)) * M + m0;
    *reinterpret_cast<uint4*>(&TpT[gb]) = make_uint4(dwv[0], dwv[1], dwv[2], dwv[3]);
    *reinterpret_cast<uint4*>(&TpT[gb + 8]) = make_uint4(dwv[4], dwv[5], dwv[6], dwv[7]);
    *reinterpret_cast<uint4*>(&TpT[gb + 16]) =
        make_uint4(dwv[8], dwv[9], dwv[10], dwv[11]);
    *reinterpret_cast<uint4*>(&TpT[gb + 24]) =
        make_uint4(dwv[12], dwv[13], dwv[14], dwv[15]);
  }
}

// ---------------------------------------------------------------------------
// K6: out[b,n,d] = sum_m En[b,n,m] * TpT[b,d,m]   (MFMA, K=64)
// grid (D/64, N/64, B), block 256
__global__ __launch_bounds__(256) void k6_unpool(
    const unsigned short* __restrict__ En, const unsigned short* __restrict__ TpT,
    float* __restrict__ out) {
  __shared__ unsigned short EnS[64][72];
  __shared__ unsigned short TpS[64][72];
  const int dt = blockIdx.x, nt = blockIdx.y, b = blockIdx.z;
  const int n0 = nt * 64, d0 = dt * 64;
  const int tid = threadIdx.x;
  const int w = tid >> 6, l = tid & 63;
#pragma unroll
  for (int p = 0; p < 2; ++p) {
    const int g = p * 256 + tid;
    const int row = g >> 3;
    const int c8 = (g & 7) * 8;
    *reinterpret_cast<short8*>(&EnS[row][c8]) =
        *reinterpret_cast<const short8*>(
            &En[((size_t)(b * N + n0 + row)) * M + c8]);
    *reinterpret_cast<short8*>(&TpS[row][c8]) =
        *reinterpret_cast<const short8*>(
            &TpT[((size_t)(b * D + d0 + row)) * M + c8]);
  }
  __syncthreads();
  floatx4 acc[4] = {{0.f, 0.f, 0.f, 0.f},
                    {0.f, 0.f, 0.f, 0.f},
                    {0.f, 0.f, 0.f, 0.f},
                    {0.f, 0.f, 0.f, 0.f}};
  const int q8 = (l >> 4) * 8;
#pragma unroll
  for (int ks = 0; ks < 2; ++ks) {
    short8 a = *reinterpret_cast<short8*>(&EnS[w * 16 + (l & 15)][ks * 32 + q8]);
#pragma unroll
    for (int dtile = 0; dtile < 4; ++dtile) {
      short8 bf = *reinterpret_cast<short8*>(
          &TpS[dtile * 16 + (l & 15)][ks * 32 + q8]);
      acc[dtile] =
          __builtin_amdgcn_mfma_f32_16x16x32_bf16(a, bf, acc[dtile], 0, 0, 0);
    }
  }
#pragma unroll
  for (int dtile = 0; dtile < 4; ++dtile)
#pragma unroll
    for (int r = 0; r < 4; ++r) {
      const int n = n0 + w * 16 + (l >> 4) * 4 + r;
      const int d = d0 + dtile * 16 + (l & 15);
      out[((size_t)(b * N + n)) * D + d] = acc[dtile][r];
    }
}

// ---------------------------------------------------------------------------
extern "C" void kernel_launch(void* const* d_in, const int* in_sizes, int n_in,
                              void* d_out, int out_size, void* d_ws,
                              size_t ws_size, hipStream_t stream) {
  const float* x = (const float*)d_in[0];
  const float* Ws = (const float*)d_in[1];
  const float* bs = (const float*)d_in[2];
  const float* Wqkv = (const float*)d_in[3];
  const float* Wo = (const float*)d_in[4];
  const float* bo = (const float*)d_in[5];
  float* out = (float*)d_out;

  char* p = (char*)d_ws;
  unsigned short* xbT = (unsigned short*)p;   p += (size_t)B * N * D * 2;   // 33.5 MB
  unsigned short* En = (unsigned short*)p;    p += (size_t)B * N * M * 2;   // 8.4 MB
  unsigned short* Et = (unsigned short*)p;    p += (size_t)B * N * M * 2;   // 8.4 MB
  unsigned short* TpT = (unsigned short*)p;   p += (size_t)B * D * M * 2;   // 128 KB
  float* denom = (float*)p;                   p += (size_t)B * M * 4;
  float* tokens = (float*)p;                  p += (size_t)B * M * D * 4;
  unsigned short* WsB = (unsigned short*)p;   p += (size_t)M * D * 2;       // 32 KB
  unsigned short* WqkvB = (unsigned short*)p; p += (size_t)3 * D * D * 2;   // 384 KB
  unsigned short* WoB = (unsigned short*)p;   p += (size_t)D * D * 2;       // 128 KB

  hipMemsetAsync(denom, 0, (size_t)B * M * sizeof(float), stream);
  hipMemsetAsync(tokens, 0, (size_t)B * M * D * sizeof(float), stream);

  k0_prep<<<dim3(136), 256, 0, stream>>>(Ws, Wqkv, Wo, WsB, WqkvB, WoB);
  k1_fused<<<dim3(N / 64, B), 256, 0, stream>>>(x, WsB, bs, xbT, En, Et, denom);
  k2_pool<<<dim3(D / 64, N / 512, B), 256, 0, stream>>>(Et, xbT, tokens);
  k_tokens<<<dim3(B), 512, 0, stream>>>(tokens, WqkvB, WoB, bo, denom, TpT);
  k6_unpool<<<dim3(D / 64, N / 64, B), 256, 0, stream>>>(En, TpT, out);
}

// Round 2
// 185.769 us; speedup vs baseline: 1.1274x; 1.1274x over previous
//
#include <hip/hip_runtime.h>
#include <math.h>

constexpr int B = 4;
constexpr int N = 16384;
constexpr int D = 256;
constexpr int M = 64;
constexpr int H = 8;
// HD = 32, 3D = 768

typedef __attribute__((ext_vector_type(8))) short short8;
typedef __attribute__((ext_vector_type(4))) float floatx4;

__device__ __forceinline__ float4 ld4(const float* p) {
  return *reinterpret_cast<const float4*>(p);
}
__device__ __forceinline__ unsigned short f2bf(float f) {
  unsigned u = __float_as_uint(f);
  unsigned r = (u + 0x7fffu + ((u >> 16) & 1u)) >> 16;  // RNE
  return (unsigned short)r;
}

// ---------------------------------------------------------------------------
// K0: one-time fp32 -> bf16 conversion of Ws (64x256), Wqkv (768x256),
// Wo (256x256). 34816 groups of 8 floats; grid 136 x 256 covers exactly.
__global__ __launch_bounds__(256) void k0_prep(
    const float* __restrict__ Ws, const float* __restrict__ Wqkv,
    const float* __restrict__ Wo, unsigned short* __restrict__ WsB,
    unsigned short* __restrict__ WqkvB, unsigned short* __restrict__ WoB) {
  const int g = blockIdx.x * 256 + threadIdx.x;
  const float* src;
  unsigned short* dst;
  int off;
  if (g < 2048) {
    src = Ws; dst = WsB; off = g;
  } else if (g < 26624) {
    src = Wqkv; dst = WqkvB; off = g - 2048;
  } else {
    src = Wo; dst = WoB; off = g - 26624;
  }
  const float4 a = ld4(&src[(size_t)off * 8]);
  const float4 c = ld4(&src[(size_t)off * 8 + 4]);
  unsigned d0 = (unsigned)f2bf(a.x) | ((unsigned)f2bf(a.y) << 16);
  unsigned d1 = (unsigned)f2bf(a.z) | ((unsigned)f2bf(a.w) << 16);
  unsigned d2 = (unsigned)f2bf(c.x) | ((unsigned)f2bf(c.y) << 16);
  unsigned d3 = (unsigned)f2bf(c.z) | ((unsigned)f2bf(c.w) << 16);
  *reinterpret_cast<uint4*>(&dst[(size_t)off * 8]) = make_uint4(d0, d1, d2, d3);
}

// ---------------------------------------------------------------------------
// K1: logits GEMM + exp + En emit. No Xt staging (each thread bulk-loads its
// own x row slice into registers up front -> 16 outstanding 16B loads/thread),
// no xbT, no Et. Writes only En (8.4 MB) + denom atomics.
// LDS: Wt 33.8K + Es 9.2K + red = 43.3 KB -> 3 blocks/CU.
// grid (N/64, B), block 256 (4 waves)
__global__ __launch_bounds__(256, 3) void k1_fused(
    const float* __restrict__ x, const unsigned short* __restrict__ WsB,
    const float* __restrict__ bs, unsigned short* __restrict__ En,
    float* __restrict__ denom) {
  __shared__ unsigned short Wt[64][264];  // Ws [m][d] bf16
  __shared__ unsigned short Es[64][72];   // E tile [n][m] bf16
  __shared__ float red[64];
  const int b = blockIdx.y;
  const int n0 = blockIdx.x * 64;
  const int tid = threadIdx.x;
  const int w = tid >> 6, l = tid & 63;
  const int l15 = l & 15;
  const int q8 = (l >> 4) * 8;     // bf16-element offset within K-group
  const int ar = w * 16 + l15;     // this thread's x row (A-frag i index)

  // Issue all x loads first: thread owns row ar, cols ks*32+q8 .. +7 (floats)
  float4 fx[16];
  const float* xrow = &x[((size_t)(b * N + n0 + ar)) * D];
#pragma unroll
  for (int ks = 0; ks < 8; ++ks) {
    fx[2 * ks] = ld4(&xrow[ks * 32 + q8]);
    fx[2 * ks + 1] = ld4(&xrow[ks * 32 + q8 + 4]);
  }
  // Stage Ws (bf16, 32 KB) -> Wt
#pragma unroll
  for (int p = 0; p < 8; ++p) {
    const int u = p * 256 + tid;
    const int row = u >> 5;          // 0..63
    const int c = (u & 31) * 8;      // 0..248
    *reinterpret_cast<short8*>(&Wt[row][c]) =
        *reinterpret_cast<const short8*>(&WsB[(size_t)row * 256 + c]);
  }
  if (tid < 64) red[tid] = 0.0f;
  __syncthreads();

  // Convert x regs -> bf16 A-frags
  short8 afr[8];
#pragma unroll
  for (int ks = 0; ks < 8; ++ks) {
    const float4 a0 = fx[2 * ks], a1 = fx[2 * ks + 1];
    short8 t;
    t[0] = (short)f2bf(a0.x); t[1] = (short)f2bf(a0.y);
    t[2] = (short)f2bf(a0.z); t[3] = (short)f2bf(a0.w);
    t[4] = (short)f2bf(a1.x); t[5] = (short)f2bf(a1.y);
    t[6] = (short)f2bf(a1.z); t[7] = (short)f2bf(a1.w);
    afr[ks] = t;
  }

  // MFMA logits GEMM: C[n, m] = sum_d x[n,d] * Ws[m,d]
  floatx4 acc[4] = {{0.f, 0.f, 0.f, 0.f},
                    {0.f, 0.f, 0.f, 0.f},
                    {0.f, 0.f, 0.f, 0.f},
                    {0.f, 0.f, 0.f, 0.f}};
#pragma unroll
  for (int ks = 0; ks < 8; ++ks) {
#pragma unroll
    for (int mt = 0; mt < 4; ++mt) {
      short8 bf = *reinterpret_cast<short8*>(&Wt[mt * 16 + l15][ks * 32 + q8]);
      acc[mt] = __builtin_amdgcn_mfma_f32_16x16x32_bf16(afr[ks], bf, acc[mt], 0, 0, 0);
    }
  }

  // epilogue: exp + Es + denom partials
#pragma unroll
  for (int mt = 0; mt < 4; ++mt) {
    const int m = mt * 16 + l15;
    const float bsm = bs[m];
    float s = 0.0f;
#pragma unroll
    for (int r = 0; r < 4; ++r) {
      const int n = w * 16 + (l >> 4) * 4 + r;
      const float e = expf(acc[mt][r] + bsm);
      s += e;
      Es[n][m] = f2bf(e);
    }
    atomicAdd(&red[m], s);
  }
  __syncthreads();
  if (tid < 64) atomicAdd(&denom[b * M + tid], red[tid]);
  // En writes (row-major, coalesced b128)
#pragma unroll
  for (int p = 0; p < 2; ++p) {
    const int g = p * 256 + tid;
    const int n = g >> 3;
    const int m0 = (g & 7) * 8;
    short8 v = *reinterpret_cast<short8*>(&Es[n][m0]);
    *reinterpret_cast<short8*>(&En[((size_t)(b * N + n0 + n)) * M + m0]) = v;
  }
}

// ---------------------------------------------------------------------------
// K2: tokens_raw[b,m,d] += sum_n E[n,m] * x[n,d]   (split-K over N)
// Reads En (row-major) and x (fp32, L3-resident) directly; builds transposed
// MFMA fragments via scalar u16 column reads from [64][66]-padded LDS tiles.
// Pad 66 (132B rows): frag-read bank = 8*q8grp + j + (l15>>1) -> all 32 banks,
// 2-way dword-share only (broadcast, free).
// grid (D/64, N/512, B), block 256
__global__ __launch_bounds__(256) void k2_pool(
    const unsigned short* __restrict__ En, const float* __restrict__ x,
    float* __restrict__ tokens) {
  __shared__ unsigned short Ens[64][66];  // E tile [n][m]
  __shared__ unsigned short Xs[64][66];   // x tile [n][d-local] bf16
  const int dt = blockIdx.x, nc = blockIdx.y, b = blockIdx.z;
  const int d0 = dt * 64;
  const int tid = threadIdx.x;
  const int w = tid >> 6, l = tid & 63;
  const int l15 = l & 15;
  const int q8 = (l >> 4) * 8;
  floatx4 acc[4] = {{0.f, 0.f, 0.f, 0.f},
                    {0.f, 0.f, 0.f, 0.f},
                    {0.f, 0.f, 0.f, 0.f},
                    {0.f, 0.f, 0.f, 0.f}};
  for (int kc = 0; kc < 8; ++kc) {
    const int nb = nc * 512 + kc * 64;
    __syncthreads();
    // stage En tile [64n][64m] bf16 (rows 132B -> 4B-aligned uint writes)
#pragma unroll
    for (int p = 0; p < 2; ++p) {
      const int u = p * 256 + tid;
      const int n = u >> 3;
      const int c8 = (u & 7) * 8;
      short8 v = *reinterpret_cast<const short8*>(
          &En[((size_t)(b * N + nb + n)) * M + c8]);
      uint4 uv = *reinterpret_cast<uint4*>(&v);
      unsigned* dp = reinterpret_cast<unsigned*>(&Ens[n][c8]);
      dp[0] = uv.x; dp[1] = uv.y; dp[2] = uv.z; dp[3] = uv.w;
    }
    // stage x tile [64n][64d] fp32 -> bf16
    {
      const int n = tid >> 2;             // 0..63
      const int c16 = (tid & 3) * 16;     // float col within d-tile
      const float* xp = &x[((size_t)(b * N + nb + n)) * D + d0 + c16];
#pragma unroll
      for (int q = 0; q < 4; ++q) {
        float4 v = ld4(xp + q * 4);
        unsigned u0 = (unsigned)f2bf(v.x) | ((unsigned)f2bf(v.y) << 16);
        unsigned u1 = (unsigned)f2bf(v.z) | ((unsigned)f2bf(v.w) << 16);
        unsigned* dp = reinterpret_cast<unsigned*>(&Xs[n][c16 + q * 4]);
        dp[0] = u0; dp[1] = u1;
      }
    }
    __syncthreads();
#pragma unroll
    for (int ks = 0; ks < 2; ++ks) {
      const int nf = ks * 32 + q8;
      short8 a;
#pragma unroll
      for (int j = 0; j < 8; ++j) a[j] = (short)Ens[nf + j][w * 16 + l15];
#pragma unroll
      for (int dtile = 0; dtile < 4; ++dtile) {
        short8 bf;
#pragma unroll
        for (int j = 0; j < 8; ++j) bf[j] = (short)Xs[nf + j][dtile * 16 + l15];
        acc[dtile] =
            __builtin_amdgcn_mfma_f32_16x16x32_bf16(a, bf, acc[dtile], 0, 0, 0);
      }
    }
  }
#pragma unroll
  for (int dtile = 0; dtile < 4; ++dtile)
#pragma unroll
    for (int r = 0; r < 4; ++r) {
      const int m = w * 16 + (l >> 4) * 4 + r;
      const int d = d0 + dtile * 16 + (l & 15);
      atomicAdd(&tokens[((size_t)(b * M + m)) * D + d], acc[dtile][r]);
    }
}

// ---------------------------------------------------------------------------
// K3/K5 (MFMA): Out[b,m,e] = (A[b,m,:] . W[e,:] + bias[e]) / denom[b,m]
// A fp32; W pre-converted bf16 (WB). K = 256.
// mode 0: write OutF fp32 [b,m,EC].  mode 1: write OutT bf16 [b,e,m] (EC=256).
// grid (EC/64, B), block 256
__global__ __launch_bounds__(256) void k_proj(
    const float* __restrict__ A, const unsigned short* __restrict__ WB,
    const float* __restrict__ bias, const float* __restrict__ denom,
    float* __restrict__ OutF, unsigned short* __restrict__ OutT, const int EC,
    const int mode) {
  __shared__ unsigned short At[64][264];
  __shared__ unsigned short Wt[64][264];
  __shared__ float Cs[64][68];
  const int et = blockIdx.x;
  const int b = blockIdx.y;
  const int tid = threadIdx.x;
  const int w = tid >> 6, l = tid & 63;
#pragma unroll
  for (int p = 0; p < 16; ++p) {
    const int i = p * 256 + tid;
    const int row = i >> 6;
    const int c4 = (i & 63) * 4;
    float4 av = ld4(&A[((size_t)(b * M + row)) * D + c4]);
    unsigned a0 = (unsigned)f2bf(av.x) | ((unsigned)f2bf(av.y) << 16);
    unsigned a1 = (unsigned)f2bf(av.z) | ((unsigned)f2bf(av.w) << 16);
    *reinterpret_cast<uint2*>(&At[row][c4]) = make_uint2(a0, a1);
  }
#pragma unroll
  for (int p = 0; p < 8; ++p) {
    const int u = p * 256 + tid;
    const int row = u >> 5;
    const int c = (u & 31) * 8;
    *reinterpret_cast<short8*>(&Wt[row][c]) =
        *reinterpret_cast<const short8*>(&WB[((size_t)(et * 64 + row)) * 256 + c]);
  }
  __syncthreads();
  floatx4 acc[4] = {{0.f, 0.f, 0.f, 0.f},
                    {0.f, 0.f, 0.f, 0.f},
                    {0.f, 0.f, 0.f, 0.f},
                    {0.f, 0.f, 0.f, 0.f}};
  const int ar = w * 16 + (l & 15);
  const int q8 = (l >> 4) * 8;
#pragma unroll
  for (int ks = 0; ks < 8; ++ks) {
    short8 a = *reinterpret_cast<short8*>(&At[ar][ks * 32 + q8]);
#pragma unroll
    for (int mt = 0; mt < 4; ++mt) {
      short8 bf = *reinterpret_cast<short8*>(&Wt[mt * 16 + (l & 15)][ks * 32 + q8]);
      acc[mt] = __builtin_amdgcn_mfma_f32_16x16x32_bf16(a, bf, acc[mt], 0, 0, 0);
    }
  }
  if (mode == 0) {
#pragma unroll
    for (int mt = 0; mt < 4; ++mt) {
#pragma unroll
      for (int r = 0; r < 4; ++r) {
        const int row = w * 16 + (l >> 4) * 4 + r;  // m
        const float rcp = 1.0f / denom[b * M + row];
        const int e = et * 64 + mt * 16 + (l & 15);
        OutF[((size_t)(b * M + row)) * EC + e] = acc[mt][r] * rcp;
      }
    }
  } else {
#pragma unroll
    for (int mt = 0; mt < 4; ++mt) {
#pragma unroll
      for (int r = 0; r < 4; ++r) {
        const int row = w * 16 + (l >> 4) * 4 + r;  // m
        const float rcp = 1.0f / denom[b * M + row];
        const int el = mt * 16 + (l & 15);
        const float bv = bias[et * 64 + el];
        Cs[row][el] = (acc[mt][r] + bv) * rcp;
      }
    }
    __syncthreads();
    // transposed bf16 write: OutT[b, e, m]
#pragma unroll
    for (int p = 0; p < 2; ++p) {
      const int g = p * 256 + tid;
      const int e = g >> 3;       // 0..63
      const int m0 = (g & 7) * 8;
      unsigned short bu[8];
#pragma unroll
      for (int k = 0; k < 8; ++k) bu[k] = f2bf(Cs[m0 + k][e]);
      uint4 pk;
      pk.x = (unsigned)bu[0] | ((unsigned)bu[1] << 16);
      pk.y = (unsigned)bu[2] | ((unsigned)bu[3] << 16);
      pk.z = (unsigned)bu[4] | ((unsigned)bu[5] << 16);
      pk.w = (unsigned)bu[6] | ((unsigned)bu[7] << 16);
      *reinterpret_cast<uint4*>(
          &OutT[((size_t)(b * D + et * 64 + e)) * M + m0]) = pk;
    }
  }
}

// ---------------------------------------------------------------------------
// K4: per (b,h) attention over M=64 tokens, HD=32 (fp32)
// grid (B*H), block 256
__global__ __launch_bounds__(256) void k4_attn(
    const float* __restrict__ qkv, float* __restrict__ attn_o) {
  __shared__ float qt[32][68];
  __shared__ float kt[32][68];
  __shared__ float vv[64][36];
  __shared__ float P[64][68];
  const int b = blockIdx.x >> 3;
  const int h = blockIdx.x & 7;
  const int tid = threadIdx.x;
  for (int i = tid; i < 512; i += 256) {
    const int m = i >> 3;
    const int c4 = (i & 7) * 4;
    const float* base = &qkv[((size_t)(b * M + m)) * 768 + h * 32 + c4];
    float4 q4 = ld4(base);
    float4 k4 = ld4(base + 256);
    float4 v4 = ld4(base + 512);
    qt[c4 + 0][m] = q4.x; qt[c4 + 1][m] = q4.y; qt[c4 + 2][m] = q4.z; qt[c4 + 3][m] = q4.w;
    kt[c4 + 0][m] = k4.x; kt[c4 + 1][m] = k4.y; kt[c4 + 2][m] = k4.z; kt[c4 + 3][m] = k4.w;
    *reinterpret_cast<float4*>(&vv[m][c4]) = v4;
  }
  __syncthreads();
  {
    const int tm4 = (tid & 15) * 4;
    const int tn4 = (tid >> 4) * 4;
    float acc[4][4] = {};
    for (int k = 0; k < 32; ++k) {
      float4 a4 = ld4(&qt[k][tn4]);
      float4 b4 = ld4(&kt[k][tm4]);
#pragma unroll
      for (int i = 0; i < 4; ++i) {
        const float av = (i == 0) ? a4.x : (i == 1) ? a4.y : (i == 2) ? a4.z : a4.w;
        acc[i][0] = fmaf(av, b4.x, acc[i][0]);
        acc[i][1] = fmaf(av, b4.y, acc[i][1]);
        acc[i][2] = fmaf(av, b4.z, acc[i][2]);
        acc[i][3] = fmaf(av, b4.w, acc[i][3]);
      }
    }
    const float scale = 0.17677669529663687f;
#pragma unroll
    for (int i = 0; i < 4; ++i)
      *reinterpret_cast<float4*>(&P[tn4 + i][tm4]) =
          make_float4(acc[i][0] * scale, acc[i][1] * scale, acc[i][2] * scale,
                      acc[i][3] * scale);
  }
  __syncthreads();
  if (tid < 64) {
    float mx = -1e30f;
    for (int j = 0; j < 64; ++j) mx = fmaxf(mx, P[tid][j]);
    float s = 0.0f;
    for (int j = 0; j < 64; ++j) {
      const float e = expf(P[tid][j] - mx);
      P[tid][j] = e;
      s += e;
    }
    const float r = 1.0f / s;
    for (int j = 0; j < 64; ++j) P[tid][j] *= r;
  }
  __syncthreads();
  if (tid < 128) {
    const int i0 = (tid >> 3) * 4;
    const int c0 = (tid & 7) * 4;
    float o[4][4] = {};
    for (int j = 0; j < 64; ++j) {
      float4 v4 = ld4(&vv[j][c0]);
#pragma unroll
      for (int ii = 0; ii < 4; ++ii) {
        const float p = P[i0 + ii][j];
        o[ii][0] = fmaf(p, v4.x, o[ii][0]);
        o[ii][1] = fmaf(p, v4.y, o[ii][1]);
        o[ii][2] = fmaf(p, v4.z, o[ii][2]);
        o[ii][3] = fmaf(p, v4.w, o[ii][3]);
      }
    }
#pragma unroll
    for (int ii = 0; ii < 4; ++ii)
      *reinterpret_cast<float4*>(
          &attn_o[((size_t)(b * M + i0 + ii)) * D + h * 32 + c0]) =
          make_float4(o[ii][0], o[ii][1], o[ii][2], o[ii][3]);
  }
}

// ---------------------------------------------------------------------------
// K6: out[b,n,d] = sum_m En[b,n,m] * TpT[b,d,m]   (MFMA, K=64)
// grid (D/64, N/64, B), block 256
__global__ __launch_bounds__(256) void k6_unpool(
    const unsigned short* __restrict__ En, const unsigned short* __restrict__ TpT,
    float* __restrict__ out) {
  __shared__ unsigned short EnS[64][72];
  __shared__ unsigned short TpS[64][72];
  const int dt = blockIdx.x, nt = blockIdx.y, b = blockIdx.z;
  const int n0 = nt * 64, d0 = dt * 64;
  const int tid = threadIdx.x;
  const int w = tid >> 6, l = tid & 63;
#pragma unroll
  for (int p = 0; p < 2; ++p) {
    const int g = p * 256 + tid;
    const int row = g >> 3;
    const int c8 = (g & 7) * 8;
    *reinterpret_cast<short8*>(&EnS[row][c8]) =
        *reinterpret_cast<const short8*>(
            &En[((size_t)(b * N + n0 + row)) * M + c8]);
    *reinterpret_cast<short8*>(&TpS[row][c8]) =
        *reinterpret_cast<const short8*>(
            &TpT[((size_t)(b * D + d0 + row)) * M + c8]);
  }
  __syncthreads();
  floatx4 acc[4] = {{0.f, 0.f, 0.f, 0.f},
                    {0.f, 0.f, 0.f, 0.f},
                    {0.f, 0.f, 0.f, 0.f},
                    {0.f, 0.f, 0.f, 0.f}};
  const int q8 = (l >> 4) * 8;
#pragma unroll
  for (int ks = 0; ks < 2; ++ks) {
    short8 a = *reinterpret_cast<short8*>(&EnS[w * 16 + (l & 15)][ks * 32 + q8]);
#pragma unroll
    for (int dtile = 0; dtile < 4; ++dtile) {
      short8 bf = *reinterpret_cast<short8*>(
          &TpS[dtile * 16 + (l & 15)][ks * 32 + q8]);
      acc[dtile] =
          __builtin_amdgcn_mfma_f32_16x16x32_bf16(a, bf, acc[dtile], 0, 0, 0);
    }
  }
#pragma unroll
  for (int dtile = 0; dtile < 4; ++dtile)
#pragma unroll
    for (int r = 0; r < 4; ++r) {
      const int n = n0 + w * 16 + (l >> 4) * 4 + r;
      const int d = d0 + dtile * 16 + (l & 15);
      out[((size_t)(b * N + n)) * D + d] = acc[dtile][r];
    }
}

// ---------------------------------------------------------------------------
extern "C" void kernel_launch(void* const* d_in, const int* in_sizes, int n_in,
                              void* d_out, int out_size, void* d_ws,
                              size_t ws_size, hipStream_t stream) {
  const float* x = (const float*)d_in[0];
  const float* Ws = (const float*)d_in[1];
  const float* bs = (const float*)d_in[2];
  const float* Wqkv = (const float*)d_in[3];
  const float* Wo = (const float*)d_in[4];
  const float* bo = (const float*)d_in[5];
  float* out = (float*)d_out;

  char* p = (char*)d_ws;
  unsigned short* En = (unsigned short*)p;    p += (size_t)B * N * M * 2;   // 8.4 MB
  unsigned short* TpT = (unsigned short*)p;   p += (size_t)B * D * M * 2;   // 128 KB
  float* denom = (float*)p;                   p += (size_t)B * M * 4;
  float* tokens = (float*)p;                  p += (size_t)B * M * D * 4;
  float* qkv = (float*)p;                     p += (size_t)B * M * 3 * D * 4;
  float* attn_o = (float*)p;                  p += (size_t)B * M * D * 4;
  unsigned short* WsB = (unsigned short*)p;   p += (size_t)M * D * 2;       // 32 KB
  unsigned short* WqkvB = (unsigned short*)p; p += (size_t)3 * D * D * 2;   // 384 KB
  unsigned short* WoB = (unsigned short*)p;   p += (size_t)D * D * 2;       // 128 KB

  hipMemsetAsync(denom, 0, (size_t)B * M * sizeof(float), stream);
  hipMemsetAsync(tokens, 0, (size_t)B * M * D * sizeof(float), stream);

  k0_prep<<<dim3(136), 256, 0, stream>>>(Ws, Wqkv, Wo, WsB, WqkvB, WoB);
  k1_fused<<<dim3(N / 64, B), 256, 0, stream>>>(x, WsB, bs, En, denom);
  k2_pool<<<dim3(D / 64, N / 512, B), 256, 0, stream>>>(En, x, tokens);
  k_proj<<<dim3(12, B), 256, 0, stream>>>(tokens, WqkvB, nullptr, denom, qkv,
                                          nullptr, 768, 0);
  k4_attn<<<dim3(B * H), 256, 0, stream>>>(qkv, attn_o);
  k_proj<<<dim3(4, B), 256, 0, stream>>>(attn_o, WoB, bo, denom, nullptr, TpT,
                                         256, 1);
  k6_unpool<<<dim3(D / 64, N / 64, B), 256, 0, stream>>>(En, TpT, out);
}

// Round 3
// 180.092 us; speedup vs baseline: 1.1630x; 1.0315x over previous
//
#include <hip/hip_runtime.h>
#include <math.h>

constexpr int B = 4;
constexpr int N = 16384;
constexpr int D = 256;
constexpr int M = 64;
constexpr int H = 8;
// HD = 32, 3D = 768

typedef __attribute__((ext_vector_type(8))) short short8;
typedef __attribute__((ext_vector_type(4))) float floatx4;

__device__ __forceinline__ float4 ld4(const float* p) {
  return *reinterpret_cast<const float4*>(p);
}
__device__ __forceinline__ unsigned short f2bf(float f) {
  unsigned u = __float_as_uint(f);
  unsigned r = (u + 0x7fffu + ((u >> 16) & 1u)) >> 16;  // RNE
  return (unsigned short)r;
}

// ---------------------------------------------------------------------------
// K0: one-time fp32 -> bf16 conversion of Ws (64x256), Wqkv (768x256),
// Wo (256x256); also zeroes denom (256 f) and tokens (65536 f) so no
// separate memsets are needed. 34816 groups of 8 floats; grid 136 x 256.
__global__ __launch_bounds__(256) void k0_prep(
    const float* __restrict__ Ws, const float* __restrict__ Wqkv,
    const float* __restrict__ Wo, unsigned short* __restrict__ WsB,
    unsigned short* __restrict__ WqkvB, unsigned short* __restrict__ WoB,
    float* __restrict__ denom, float* __restrict__ tokens) {
  const int g = blockIdx.x * 256 + threadIdx.x;
  if (g < 32768)
    *reinterpret_cast<float2*>(&tokens[g * 2]) = make_float2(0.f, 0.f);
  if (g < 128)
    *reinterpret_cast<float2*>(&denom[g * 2]) = make_float2(0.f, 0.f);
  const float* src;
  unsigned short* dst;
  int off;
  if (g < 2048) {
    src = Ws; dst = WsB; off = g;
  } else if (g < 26624) {
    src = Wqkv; dst = WqkvB; off = g - 2048;
  } else {
    src = Wo; dst = WoB; off = g - 26624;
  }
  const float4 a = ld4(&src[(size_t)off * 8]);
  const float4 c = ld4(&src[(size_t)off * 8 + 4]);
  unsigned d0 = (unsigned)f2bf(a.x) | ((unsigned)f2bf(a.y) << 16);
  unsigned d1 = (unsigned)f2bf(a.z) | ((unsigned)f2bf(a.w) << 16);
  unsigned d2 = (unsigned)f2bf(c.x) | ((unsigned)f2bf(c.y) << 16);
  unsigned d3 = (unsigned)f2bf(c.z) | ((unsigned)f2bf(c.w) << 16);
  *reinterpret_cast<uint4*>(&dst[(size_t)off * 8]) = make_uint4(d0, d1, d2, d3);
}

// ---------------------------------------------------------------------------
// K1: logits GEMM + exp + En emit. 128-row tiles, 8 waves; Wt staged once
// per 128 rows; x rows bulk-loaded to regs; En stored directly from acc
// (no Es LDS round-trip). LDS = 34 KB; VGPR capped 128 -> 16 waves/CU.
// grid (N/128, B), block 512
__global__ __launch_bounds__(512, 4) void k1_fused(
    const float* __restrict__ x, const unsigned short* __restrict__ WsB,
    const float* __restrict__ bs, unsigned short* __restrict__ En,
    float* __restrict__ denom) {
  __shared__ unsigned short Wt[64][264];  // Ws [m][d] bf16
  __shared__ float red[64];
  const int b = blockIdx.y;
  const int n0 = blockIdx.x * 128;
  const int tid = threadIdx.x;
  const int w = tid >> 6, l = tid & 63;
  const int l15 = l & 15;
  const int q8 = (l >> 4) * 8;     // bf16-element offset within K-group
  const int ar = w * 16 + l15;     // this thread's x row (0..127)

  // Issue all x loads first: thread owns row ar, cols ks*32+q8 .. +7 (floats)
  float4 fx[16];
  const float* xrow = &x[((size_t)(b * N + n0 + ar)) * D];
#pragma unroll
  for (int ks = 0; ks < 8; ++ks) {
    fx[2 * ks] = ld4(&xrow[ks * 32 + q8]);
    fx[2 * ks + 1] = ld4(&xrow[ks * 32 + q8 + 4]);
  }
  // Stage Ws (bf16, 32 KB) -> Wt
#pragma unroll
  for (int p = 0; p < 4; ++p) {
    const int u = p * 512 + tid;
    const int row = u >> 5;          // 0..63
    const int c = (u & 31) * 8;      // 0..248
    *reinterpret_cast<short8*>(&Wt[row][c]) =
        *reinterpret_cast<const short8*>(&WsB[(size_t)row * 256 + c]);
  }
  if (tid < 64) red[tid] = 0.0f;

  // Convert x regs -> bf16 A-frags
  short8 afr[8];
#pragma unroll
  for (int ks = 0; ks < 8; ++ks) {
    const float4 a0 = fx[2 * ks], a1 = fx[2 * ks + 1];
    short8 t;
    t[0] = (short)f2bf(a0.x); t[1] = (short)f2bf(a0.y);
    t[2] = (short)f2bf(a0.z); t[3] = (short)f2bf(a0.w);
    t[4] = (short)f2bf(a1.x); t[5] = (short)f2bf(a1.y);
    t[6] = (short)f2bf(a1.z); t[7] = (short)f2bf(a1.w);
    afr[ks] = t;
  }
  __syncthreads();

  // MFMA logits GEMM: C[n, m] = sum_d x[n,d] * Ws[m,d]
  floatx4 acc[4] = {{0.f, 0.f, 0.f, 0.f},
                    {0.f, 0.f, 0.f, 0.f},
                    {0.f, 0.f, 0.f, 0.f},
                    {0.f, 0.f, 0.f, 0.f}};
#pragma unroll
  for (int ks = 0; ks < 8; ++ks) {
#pragma unroll
    for (int mt = 0; mt < 4; ++mt) {
      short8 bf = *reinterpret_cast<short8*>(&Wt[mt * 16 + l15][ks * 32 + q8]);
      acc[mt] = __builtin_amdgcn_mfma_f32_16x16x32_bf16(afr[ks], bf, acc[mt], 0, 0, 0);
    }
  }

  // epilogue: exp + direct En stores + denom partials
#pragma unroll
  for (int mt = 0; mt < 4; ++mt) {
    const int m = mt * 16 + l15;
    const float bsm = bs[m];
    float s = 0.0f;
#pragma unroll
    for (int r = 0; r < 4; ++r) {
      const int n = w * 16 + (l >> 4) * 4 + r;
      const float e = expf(acc[mt][r] + bsm);
      s += e;
      En[((size_t)(b * N + n0 + n)) * M + m] = f2bf(e);
    }
    atomicAdd(&red[m], s);
  }
  __syncthreads();
  if (tid < 64) atomicAdd(&denom[b * M + tid], red[tid]);
}

// ---------------------------------------------------------------------------
// K2: tokens_raw[b,m,d] += sum_n E[n,m] * x[n,d]   (split-K over N)
// x transposed at LDS-WRITE time (16 scalar u16 writes/thread) so B-frags
// are ds_read_b128 from XsT[d][n] (pad 72 -> 2-way). En staged row-major
// with pad 70 (stride 35 dwords) so A-frag scalar column reads hit all 32
// banks 1-way. Chunk = 256 n-rows -> 1024 blocks (4/CU).
// grid (D/64, N/256, B), block 256
__global__ __launch_bounds__(256) void k2_pool(
    const unsigned short* __restrict__ En, const float* __restrict__ x,
    float* __restrict__ tokens) {
  __shared__ unsigned short Ens[64][70];  // E tile [n][m]
  __shared__ unsigned short XsT[64][72];  // x tile [d-local][n] bf16
  const int dt = blockIdx.x, nc = blockIdx.y, b = blockIdx.z;
  const int d0 = dt * 64;
  const int tid = threadIdx.x;
  const int w = tid >> 6, l = tid & 63;
  const int l15 = l & 15;
  const int q8 = (l >> 4) * 8;
  floatx4 acc[4] = {{0.f, 0.f, 0.f, 0.f},
                    {0.f, 0.f, 0.f, 0.f},
                    {0.f, 0.f, 0.f, 0.f},
                    {0.f, 0.f, 0.f, 0.f}};
  for (int kc = 0; kc < 4; ++kc) {
    const int nb = nc * 256 + kc * 64;
    __syncthreads();
    // stage En tile [64n][64m] bf16
#pragma unroll
    for (int p = 0; p < 2; ++p) {
      const int u = p * 256 + tid;
      const int n = u >> 3;
      const int c8 = (u & 7) * 8;
      short8 v = *reinterpret_cast<const short8*>(
          &En[((size_t)(b * N + nb + n)) * M + c8]);
      uint4 uv = *reinterpret_cast<uint4*>(&v);
      unsigned* dp = reinterpret_cast<unsigned*>(&Ens[n][c8]);
      dp[0] = uv.x; dp[1] = uv.y; dp[2] = uv.z; dp[3] = uv.w;
    }
    // stage x tile transposed: XsT[d-local][n] (fp32 -> bf16)
    {
      const int n = tid >> 2;             // 0..63
      const int c16 = (tid & 3) * 16;     // d-local base
      const float* xp = &x[((size_t)(b * N + nb + n)) * D + d0 + c16];
#pragma unroll
      for (int q = 0; q < 4; ++q) {
        float4 v = ld4(xp + q * 4);
        XsT[c16 + q * 4 + 0][n] = f2bf(v.x);
        XsT[c16 + q * 4 + 1][n] = f2bf(v.y);
        XsT[c16 + q * 4 + 2][n] = f2bf(v.z);
        XsT[c16 + q * 4 + 3][n] = f2bf(v.w);
      }
    }
    __syncthreads();
#pragma unroll
    for (int ks = 0; ks < 2; ++ks) {
      const int nf = ks * 32 + q8;
      short8 a;
#pragma unroll
      for (int j = 0; j < 8; ++j) a[j] = (short)Ens[nf + j][w * 16 + l15];
#pragma unroll
      for (int dtile = 0; dtile < 4; ++dtile) {
        short8 bf = *reinterpret_cast<short8*>(&XsT[dtile * 16 + l15][nf]);
        acc[dtile] =
            __builtin_amdgcn_mfma_f32_16x16x32_bf16(a, bf, acc[dtile], 0, 0, 0);
      }
    }
  }
#pragma unroll
  for (int dtile = 0; dtile < 4; ++dtile)
#pragma unroll
    for (int r = 0; r < 4; ++r) {
      const int m = w * 16 + (l >> 4) * 4 + r;
      const int d = d0 + dtile * 16 + (l & 15);
      atomicAdd(&tokens[((size_t)(b * M + m)) * D + d], acc[dtile][r]);
    }
}

// ---------------------------------------------------------------------------
// K3/K5 (MFMA): Out[b,m,e] = (A[b,m,:] . W[e,:] + bias[e]) / denom[b,m]
// A fp32; W pre-converted bf16 (WB). K = 256.
// mode 0: write OutF fp32 [b,m,EC].  mode 1: write OutT bf16 [b,e,m] (EC=256).
// grid (EC/64, B), block 256
__global__ __launch_bounds__(256) void k_proj(
    const float* __restrict__ A, const unsigned short* __restrict__ WB,
    const float* __restrict__ bias, const float* __restrict__ denom,
    float* __restrict__ OutF, unsigned short* __restrict__ OutT, const int EC,
    const int mode) {
  __shared__ unsigned short At[64][264];
  __shared__ unsigned short Wt[64][264];
  __shared__ float Cs[64][68];
  const int et = blockIdx.x;
  const int b = blockIdx.y;
  const int tid = threadIdx.x;
  const int w = tid >> 6, l = tid & 63;
#pragma unroll
  for (int p = 0; p < 16; ++p) {
    const int i = p * 256 + tid;
    const int row = i >> 6;
    const int c4 = (i & 63) * 4;
    float4 av = ld4(&A[((size_t)(b * M + row)) * D + c4]);
    unsigned a0 = (unsigned)f2bf(av.x) | ((unsigned)f2bf(av.y) << 16);
    unsigned a1 = (unsigned)f2bf(av.z) | ((unsigned)f2bf(av.w) << 16);
    *reinterpret_cast<uint2*>(&At[row][c4]) = make_uint2(a0, a1);
  }
#pragma unroll
  for (int p = 0; p < 8; ++p) {
    const int u = p * 256 + tid;
    const int row = u >> 5;
    const int c = (u & 31) * 8;
    *reinterpret_cast<short8*>(&Wt[row][c]) =
        *reinterpret_cast<const short8*>(&WB[((size_t)(et * 64 + row)) * 256 + c]);
  }
  __syncthreads();
  floatx4 acc[4] = {{0.f, 0.f, 0.f, 0.f},
                    {0.f, 0.f, 0.f, 0.f},
                    {0.f, 0.f, 0.f, 0.f},
                    {0.f, 0.f, 0.f, 0.f}};
  const int ar = w * 16 + (l & 15);
  const int q8 = (l >> 4) * 8;
#pragma unroll
  for (int ks = 0; ks < 8; ++ks) {
    short8 a = *reinterpret_cast<short8*>(&At[ar][ks * 32 + q8]);
#pragma unroll
    for (int mt = 0; mt < 4; ++mt) {
      short8 bf = *reinterpret_cast<short8*>(&Wt[mt * 16 + (l & 15)][ks * 32 + q8]);
      acc[mt] = __builtin_amdgcn_mfma_f32_16x16x32_bf16(a, bf, acc[mt], 0, 0, 0);
    }
  }
  if (mode == 0) {
#pragma unroll
    for (int mt = 0; mt < 4; ++mt) {
#pragma unroll
      for (int r = 0; r < 4; ++r) {
        const int row = w * 16 + (l >> 4) * 4 + r;  // m
        const float rcp = 1.0f / denom[b * M + row];
        const int e = et * 64 + mt * 16 + (l & 15);
        OutF[((size_t)(b * M + row)) * EC + e] = acc[mt][r] * rcp;
      }
    }
  } else {
#pragma unroll
    for (int mt = 0; mt < 4; ++mt) {
#pragma unroll
      for (int r = 0; r < 4; ++r) {
        const int row = w * 16 + (l >> 4) * 4 + r;  // m
        const float rcp = 1.0f / denom[b * M + row];
        const int el = mt * 16 + (l & 15);
        const float bv = bias[et * 64 + el];
        Cs[row][el] = (acc[mt][r] + bv) * rcp;
      }
    }
    __syncthreads();
    // transposed bf16 write: OutT[b, e, m]
#pragma unroll
    for (int p = 0; p < 2; ++p) {
      const int g = p * 256 + tid;
      const int e = g >> 3;       // 0..63
      const int m0 = (g & 7) * 8;
      unsigned short bu[8];
#pragma unroll
      for (int k = 0; k < 8; ++k) bu[k] = f2bf(Cs[m0 + k][e]);
      uint4 pk;
      pk.x = (unsigned)bu[0] | ((unsigned)bu[1] << 16);
      pk.y = (unsigned)bu[2] | ((unsigned)bu[3] << 16);
      pk.z = (unsigned)bu[4] | ((unsigned)bu[5] << 16);
      pk.w = (unsigned)bu[6] | ((unsigned)bu[7] << 16);
      *reinterpret_cast<uint4*>(
          &OutT[((size_t)(b * D + et * 64 + e)) * M + m0]) = pk;
    }
  }
}

// ---------------------------------------------------------------------------
// K4: per (b,h) attention over M=64 tokens, HD=32 (fp32)
// grid (B*H), block 256
__global__ __launch_bounds__(256) void k4_attn(
    const float* __restrict__ qkv, float* __restrict__ attn_o) {
  __shared__ float qt[32][68];
  __shared__ float kt[32][68];
  __shared__ float vv[64][36];
  __shared__ float P[64][68];
  const int b = blockIdx.x >> 3;
  const int h = blockIdx.x & 7;
  const int tid = threadIdx.x;
  for (int i = tid; i < 512; i += 256) {
    const int m = i >> 3;
    const int c4 = (i & 7) * 4;
    const float* base = &qkv[((size_t)(b * M + m)) * 768 + h * 32 + c4];
    float4 q4 = ld4(base);
    float4 k4 = ld4(base + 256);
    float4 v4 = ld4(base + 512);
    qt[c4 + 0][m] = q4.x; qt[c4 + 1][m] = q4.y; qt[c4 + 2][m] = q4.z; qt[c4 + 3][m] = q4.w;
    kt[c4 + 0][m] = k4.x; kt[c4 + 1][m] = k4.y; kt[c4 + 2][m] = k4.z; kt[c4 + 3][m] = k4.w;
    *reinterpret_cast<float4*>(&vv[m][c4]) = v4;
  }
  __syncthreads();
  {
    const int tm4 = (tid & 15) * 4;
    const int tn4 = (tid >> 4) * 4;
    float acc[4][4] = {};
    for (int k = 0; k < 32; ++k) {
      float4 a4 = ld4(&qt[k][tn4]);
      float4 b4 = ld4(&kt[k][tm4]);
#pragma unroll
      for (int i = 0; i < 4; ++i) {
        const float av = (i == 0) ? a4.x : (i == 1) ? a4.y : (i == 2) ? a4.z : a4.w;
        acc[i][0] = fmaf(av, b4.x, acc[i][0]);
        acc[i][1] = fmaf(av, b4.y, acc[i][1]);
        acc[i][2] = fmaf(av, b4.z, acc[i][2]);
        acc[i][3] = fmaf(av, b4.w, acc[i][3]);
      }
    }
    const float scale = 0.17677669529663687f;
#pragma unroll
    for (int i = 0; i < 4; ++i)
      *reinterpret_cast<float4*>(&P[tn4 + i][tm4]) =
          make_float4(acc[i][0] * scale, acc[i][1] * scale, acc[i][2] * scale,
                      acc[i][3] * scale);
  }
  __syncthreads();
  if (tid < 64) {
    float mx = -1e30f;
    for (int j = 0; j < 64; ++j) mx = fmaxf(mx, P[tid][j]);
    float s = 0.0f;
    for (int j = 0; j < 64; ++j) {
      const float e = expf(P[tid][j] - mx);
      P[tid][j] = e;
      s += e;
    }
    const float r = 1.0f / s;
    for (int j = 0; j < 64; ++j) P[tid][j] *= r;
  }
  __syncthreads();
  if (tid < 128) {
    const int i0 = (tid >> 3) * 4;
    const int c0 = (tid & 7) * 4;
    float o[4][4] = {};
    for (int j = 0; j < 64; ++j) {
      float4 v4 = ld4(&vv[j][c0]);
#pragma unroll
      for (int ii = 0; ii < 4; ++ii) {
        const float p = P[i0 + ii][j];
        o[ii][0] = fmaf(p, v4.x, o[ii][0]);
        o[ii][1] = fmaf(p, v4.y, o[ii][1]);
        o[ii][2] = fmaf(p, v4.z, o[ii][2]);
        o[ii][3] = fmaf(p, v4.w, o[ii][3]);
      }
    }
#pragma unroll
    for (int ii = 0; ii < 4; ++ii)
      *reinterpret_cast<float4*>(
          &attn_o[((size_t)(b * M + i0 + ii)) * D + h * 32 + c0]) =
          make_float4(o[ii][0], o[ii][1], o[ii][2], o[ii][3]);
  }
}

// ---------------------------------------------------------------------------
// K6: out[b,n,d] = sum_m En[b,n,m] * TpT[b,d,m]   (MFMA, K=64)
// grid (D/64, N/64, B), block 256
__global__ __launch_bounds__(256) void k6_unpool(
    const unsigned short* __restrict__ En, const unsigned short* __restrict__ TpT,
    float* __restrict__ out) {
  __shared__ unsigned short EnS[64][72];
  __shared__ unsigned short TpS[64][72];
  const int dt = blockIdx.x, nt = blockIdx.y, b = blockIdx.z;
  const int n0 = nt * 64, d0 = dt * 64;
  const int tid = threadIdx.x;
  const int w = tid >> 6, l = tid & 63;
#pragma unroll
  for (int p = 0; p < 2; ++p) {
    const int g = p * 256 + tid;
    const int row = g >> 3;
    const int c8 = (g & 7) * 8;
    *reinterpret_cast<short8*>(&EnS[row][c8]) =
        *reinterpret_cast<const short8*>(
            &En[((size_t)(b * N + n0 + row)) * M + c8]);
    *reinterpret_cast<short8*>(&TpS[row][c8]) =
        *reinterpret_cast<const short8*>(
            &TpT[((size_t)(b * D + d0 + row)) * M + c8]);
  }
  __syncthreads();
  floatx4 acc[4] = {{0.f, 0.f, 0.f, 0.f},
                    {0.f, 0.f, 0.f, 0.f},
                    {0.f, 0.f, 0.f, 0.f},
                    {0.f, 0.f, 0.f, 0.f}};
  const int q8 = (l >> 4) * 8;
#pragma unroll
  for (int ks = 0; ks < 2; ++ks) {
    short8 a = *reinterpret_cast<short8*>(&EnS[w * 16 + (l & 15)][ks * 32 + q8]);
#pragma unroll
    for (int dtile = 0; dtile < 4; ++dtile) {
      short8 bf = *reinterpret_cast<short8*>(
          &TpS[dtile * 16 + (l & 15)][ks * 32 + q8]);
      acc[dtile] =
          __builtin_amdgcn_mfma_f32_16x16x32_bf16(a, bf, acc[dtile], 0, 0, 0);
    }
  }
#pragma unroll
  for (int dtile = 0; dtile < 4; ++dtile)
#pragma unroll
    for (int r = 0; r < 4; ++r) {
      const int n = n0 + w * 16 + (l >> 4) * 4 + r;
      const int d = d0 + dtile * 16 + (l & 15);
      out[((size_t)(b * N + n)) * D + d] = acc[dtile][r];
    }
}

// ---------------------------------------------------------------------------
extern "C" void kernel_launch(void* const* d_in, const int* in_sizes, int n_in,
                              void* d_out, int out_size, void* d_ws,
                              size_t ws_size, hipStream_t stream) {
  const float* x = (const float*)d_in[0];
  const float* Ws = (const float*)d_in[1];
  const float* bs = (const float*)d_in[2];
  const float* Wqkv = (const float*)d_in[3];
  const float* Wo = (const float*)d_in[4];
  const float* bo = (const float*)d_in[5];
  float* out = (float*)d_out;

  char* p = (char*)d_ws;
  unsigned short* En = (unsigned short*)p;    p += (size_t)B * N * M * 2;   // 8.4 MB
  unsigned short* TpT = (unsigned short*)p;   p += (size_t)B * D * M * 2;   // 128 KB
  float* denom = (float*)p;                   p += (size_t)B * M * 4;
  float* tokens = (float*)p;                  p += (size_t)B * M * D * 4;
  float* qkv = (float*)p;                     p += (size_t)B * M * 3 * D * 4;
  float* attn_o = (float*)p;                  p += (size_t)B * M * D * 4;
  unsigned short* WsB = (unsigned short*)p;   p += (size_t)M * D * 2;       // 32 KB
  unsigned short* WqkvB = (unsigned short*)p; p += (size_t)3 * D * D * 2;   // 384 KB
  unsigned short* WoB = (unsigned short*)p;   p += (size_t)D * D * 2;       // 128 KB

  k0_prep<<<dim3(136), 256, 0, stream>>>(Ws, Wqkv, Wo, WsB, WqkvB, WoB,
                                         denom, tokens);
  k1_fused<<<dim3(N / 128, B), 512, 0, stream>>>(x, WsB, bs, En, denom);
  k2_pool<<<dim3(D / 64, N / 256, B), 256, 0, stream>>>(En, x, tokens);
  k_proj<<<dim3(12, B), 256, 0, stream>>>(tokens, WqkvB, nullptr, denom, qkv,
                                          nullptr, 768, 0);
  k4_attn<<<dim3(B * H), 256, 0, stream>>>(qkv, attn_o);
  k_proj<<<dim3(4, B), 256, 0, stream>>>(attn_o, WoB, bo, denom, nullptr, TpT,
                                         256, 1);
  k6_unpool<<<dim3(D / 64, N / 64, B), 256, 0, stream>>>(En, TpT, out);
}

// Round 5
// 174.605 us; speedup vs baseline: 1.1995x; 1.0314x over previous
//
#include <hip/hip_runtime.h>
#include <math.h>

constexpr int B = 4;
constexpr int N = 16384;
constexpr int D = 256;
constexpr int M = 64;
constexpr int H = 8;
// HD = 32, 3D = 768

typedef __attribute__((ext_vector_type(8))) short short8;
typedef __attribute__((ext_vector_type(4))) float floatx4;

__device__ __forceinline__ float4 ld4(const float* p) {
  return *reinterpret_cast<const float4*>(p);
}
__device__ __forceinline__ unsigned short f2bf(float f) {
  unsigned u = __float_as_uint(f);
  unsigned r = (u + 0x7fffu + ((u >> 16) & 1u)) >> 16;  // RNE
  return (unsigned short)r;
}

// ---------------------------------------------------------------------------
// K0: one-time fp32 -> bf16 conversion of Ws (64x256), Wqkv (768x256),
// Wo (256x256); also zeroes denom, tokens, tokO. grid 136 x 256.
__global__ __launch_bounds__(256) void k0_prep(
    const float* __restrict__ Ws, const float* __restrict__ Wqkv,
    const float* __restrict__ Wo, unsigned short* __restrict__ WsB,
    unsigned short* __restrict__ WqkvB, unsigned short* __restrict__ WoB,
    float* __restrict__ denom, float* __restrict__ tokens,
    float* __restrict__ tokO) {
  const int g = blockIdx.x * 256 + threadIdx.x;
  if (g < 32768) {
    *reinterpret_cast<float2*>(&tokens[g * 2]) = make_float2(0.f, 0.f);
    *reinterpret_cast<float2*>(&tokO[g * 2]) = make_float2(0.f, 0.f);
  }
  if (g < 128)
    *reinterpret_cast<float2*>(&denom[g * 2]) = make_float2(0.f, 0.f);
  const float* src;
  unsigned short* dst;
  int off;
  if (g < 2048) {
    src = Ws; dst = WsB; off = g;
  } else if (g < 26624) {
    src = Wqkv; dst = WqkvB; off = g - 2048;
  } else {
    src = Wo; dst = WoB; off = g - 26624;
  }
  const float4 a = ld4(&src[(size_t)off * 8]);
  const float4 c = ld4(&src[(size_t)off * 8 + 4]);
  unsigned d0 = (unsigned)f2bf(a.x) | ((unsigned)f2bf(a.y) << 16);
  unsigned d1 = (unsigned)f2bf(a.z) | ((unsigned)f2bf(a.w) << 16);
  unsigned d2 = (unsigned)f2bf(c.x) | ((unsigned)f2bf(c.y) << 16);
  unsigned d3 = (unsigned)f2bf(c.z) | ((unsigned)f2bf(c.w) << 16);
  *reinterpret_cast<uint4*>(&dst[(size_t)off * 8]) = make_uint4(d0, d1, d2, d3);
}

// ---------------------------------------------------------------------------
// K1: logits GEMM + exp + En emit. 128-row tiles, 8 waves; Wt staged once
// per 128 rows; x rows bulk-loaded to regs; En stored directly from acc.
// grid (N/128, B), block 512
__global__ __launch_bounds__(512, 4) void k1_fused(
    const float* __restrict__ x, const unsigned short* __restrict__ WsB,
    const float* __restrict__ bs, unsigned short* __restrict__ En,
    float* __restrict__ denom) {
  __shared__ unsigned short Wt[64][264];  // Ws [m][d] bf16
  __shared__ float red[64];
  const int b = blockIdx.y;
  const int n0 = blockIdx.x * 128;
  const int tid = threadIdx.x;
  const int w = tid >> 6, l = tid & 63;
  const int l15 = l & 15;
  const int q8 = (l >> 4) * 8;     // bf16-element offset within K-group
  const int ar = w * 16 + l15;     // this thread's x row (0..127)

  // Issue all x loads first
  float4 fx[16];
  const float* xrow = &x[((size_t)(b * N + n0 + ar)) * D];
#pragma unroll
  for (int ks = 0; ks < 8; ++ks) {
    fx[2 * ks] = ld4(&xrow[ks * 32 + q8]);
    fx[2 * ks + 1] = ld4(&xrow[ks * 32 + q8 + 4]);
  }
  // Stage Ws (bf16, 32 KB) -> Wt
#pragma unroll
  for (int p = 0; p < 4; ++p) {
    const int u = p * 512 + tid;
    const int row = u >> 5;          // 0..63
    const int c = (u & 31) * 8;      // 0..248
    *reinterpret_cast<short8*>(&Wt[row][c]) =
        *reinterpret_cast<const short8*>(&WsB[(size_t)row * 256 + c]);
  }
  if (tid < 64) red[tid] = 0.0f;

  // Convert x regs -> bf16 A-frags
  short8 afr[8];
#pragma unroll
  for (int ks = 0; ks < 8; ++ks) {
    const float4 a0 = fx[2 * ks], a1 = fx[2 * ks + 1];
    short8 t;
    t[0] = (short)f2bf(a0.x); t[1] = (short)f2bf(a0.y);
    t[2] = (short)f2bf(a0.z); t[3] = (short)f2bf(a0.w);
    t[4] = (short)f2bf(a1.x); t[5] = (short)f2bf(a1.y);
    t[6] = (short)f2bf(a1.z); t[7] = (short)f2bf(a1.w);
    afr[ks] = t;
  }
  __syncthreads();

  // MFMA logits GEMM: C[n, m] = sum_d x[n,d] * Ws[m,d]
  floatx4 acc[4] = {{0.f, 0.f, 0.f, 0.f},
                    {0.f, 0.f, 0.f, 0.f},
                    {0.f, 0.f, 0.f, 0.f},
                    {0.f, 0.f, 0.f, 0.f}};
#pragma unroll
  for (int ks = 0; ks < 8; ++ks) {
#pragma unroll
    for (int mt = 0; mt < 4; ++mt) {
      short8 bf = *reinterpret_cast<short8*>(&Wt[mt * 16 + l15][ks * 32 + q8]);
      acc[mt] = __builtin_amdgcn_mfma_f32_16x16x32_bf16(afr[ks], bf, acc[mt], 0, 0, 0);
    }
  }

  // epilogue: exp + direct En stores + denom partials
#pragma unroll
  for (int mt = 0; mt < 4; ++mt) {
    const int m = mt * 16 + l15;
    const float bsm = bs[m];
    float s = 0.0f;
#pragma unroll
    for (int r = 0; r < 4; ++r) {
      const int n = w * 16 + (l >> 4) * 4 + r;
      const float e = expf(acc[mt][r] + bsm);
      s += e;
      En[((size_t)(b * N + n0 + n)) * M + m] = f2bf(e);
    }
    atomicAdd(&red[m], s);
  }
  __syncthreads();
  if (tid < 64) atomicAdd(&denom[b * M + tid], red[tid]);
}

// ---------------------------------------------------------------------------
// K2: tokens_raw[b,m,d] += sum_n E[n,m] * x[n,d]   (split-K over N)
// grid (D/64, N/256, B), block 256
__global__ __launch_bounds__(256) void k2_pool(
    const unsigned short* __restrict__ En, const float* __restrict__ x,
    float* __restrict__ tokens) {
  __shared__ unsigned short Ens[64][70];  // E tile [n][m]
  __shared__ unsigned short XsT[64][72];  // x tile [d-local][n] bf16
  const int dt = blockIdx.x, nc = blockIdx.y, b = blockIdx.z;
  const int d0 = dt * 64;
  const int tid = threadIdx.x;
  const int w = tid >> 6, l = tid & 63;
  const int l15 = l & 15;
  const int q8 = (l >> 4) * 8;
  floatx4 acc[4] = {{0.f, 0.f, 0.f, 0.f},
                    {0.f, 0.f, 0.f, 0.f},
                    {0.f, 0.f, 0.f, 0.f},
                    {0.f, 0.f, 0.f, 0.f}};
  for (int kc = 0; kc < 4; ++kc) {
    const int nb = nc * 256 + kc * 64;
    __syncthreads();
    // stage En tile [64n][64m] bf16
#pragma unroll
    for (int p = 0; p < 2; ++p) {
      const int u = p * 256 + tid;
      const int n = u >> 3;
      const int c8 = (u & 7) * 8;
      short8 v = *reinterpret_cast<const short8*>(
          &En[((size_t)(b * N + nb + n)) * M + c8]);
      uint4 uv = *reinterpret_cast<uint4*>(&v);
      unsigned* dp = reinterpret_cast<unsigned*>(&Ens[n][c8]);
      dp[0] = uv.x; dp[1] = uv.y; dp[2] = uv.z; dp[3] = uv.w;
    }
    // stage x tile transposed: XsT[d-local][n] (fp32 -> bf16)
    {
      const int n = tid >> 2;             // 0..63
      const int c16 = (tid & 3) * 16;     // d-local base
      const float* xp = &x[((size_t)(b * N + nb + n)) * D + d0 + c16];
#pragma unroll
      for (int q = 0; q < 4; ++q) {
        float4 v = ld4(xp + q * 4);
        XsT[c16 + q * 4 + 0][n] = f2bf(v.x);
        XsT[c16 + q * 4 + 1][n] = f2bf(v.y);
        XsT[c16 + q * 4 + 2][n] = f2bf(v.z);
        XsT[c16 + q * 4 + 3][n] = f2bf(v.w);
      }
    }
    __syncthreads();
#pragma unroll
    for (int ks = 0; ks < 2; ++ks) {
      const int nf = ks * 32 + q8;
      short8 a;
#pragma unroll
      for (int j = 0; j < 8; ++j) a[j] = (short)Ens[nf + j][w * 16 + l15];
#pragma unroll
      for (int dtile = 0; dtile < 4; ++dtile) {
        short8 bf = *reinterpret_cast<short8*>(&XsT[dtile * 16 + l15][nf]);
        acc[dtile] =
            __builtin_amdgcn_mfma_f32_16x16x32_bf16(a, bf, acc[dtile], 0, 0, 0);
      }
    }
  }
#pragma unroll
  for (int dtile = 0; dtile < 4; ++dtile)
#pragma unroll
    for (int r = 0; r < 4; ++r) {
      const int m = w * 16 + (l >> 4) * 4 + r;
      const int d = d0 + dtile * 16 + (l & 15);
      atomicAdd(&tokens[((size_t)(b * M + m)) * D + d], acc[dtile][r]);
    }
}

// ---------------------------------------------------------------------------
// K_FA: fused token stage, one block per (b,h), 256 threads (each block
// effectively alone on a CU). Phases:
//   1. stage At (tokens bf16) + Wq (head slice of Wqkv, 96 rows)
//   2. GEMM1: qkv[64 m][96 e] = At x Wq^T (K=256), /denom
//   3. -> qt[hd][m], kt[hd][m], vv[m][hd] fp32 (overlay At/Wq region)
//   4. attention (fp32 FMA core, proven k4 structure)
//   5. partial out-proj (K=32 MFMA vs 4 preloaded WoB frags)
//   6. atomicAdd into tokO[b,m,d]
// grid (B*H), block 256
__global__ __launch_bounds__(256) void k_fa(
    const float* __restrict__ tokens, const unsigned short* __restrict__ WqkvB,
    const unsigned short* __restrict__ WoB, const float* __restrict__ denom,
    float* __restrict__ tokO) {
  __shared__ __align__(16) char smem[84480];
  unsigned short* const At = reinterpret_cast<unsigned short*>(smem);          // [64][264]
  unsigned short* const Wq = reinterpret_cast<unsigned short*>(smem + 33792);  // [96][264]
  float* const qt = reinterpret_cast<float*>(smem);            // [32][68]
  float* const kt = reinterpret_cast<float*>(smem + 8704);     // [32][68]
  float* const vv = reinterpret_cast<float*>(smem + 17408);    // [64][36]
  float* const P  = reinterpret_cast<float*>(smem + 26624);    // [64][68]
  float* const ao = reinterpret_cast<float*>(smem + 44032);    // [64][36]
  const int b = blockIdx.x >> 3;
  const int h = blockIdx.x & 7;
  const int tid = threadIdx.x;
  const int w = tid >> 6, l = tid & 63;
  const int l15 = l & 15;
  const int q8 = (l >> 4) * 8;
  const int r4 = (l >> 4) * 4;

  // Phase 1: stage At + Wq
#pragma unroll
  for (int p = 0; p < 16; ++p) {
    const int i = p * 256 + tid;
    const int row = i >> 6;
    const int c4 = (i & 63) * 4;
    float4 av = ld4(&tokens[((size_t)(b * M + row)) * D + c4]);
    unsigned a0 = (unsigned)f2bf(av.x) | ((unsigned)f2bf(av.y) << 16);
    unsigned a1 = (unsigned)f2bf(av.z) | ((unsigned)f2bf(av.w) << 16);
    *reinterpret_cast<uint2*>(&At[row * 264 + c4]) = make_uint2(a0, a1);
  }
#pragma unroll
  for (int p = 0; p < 12; ++p) {
    const int u = p * 256 + tid;
    const int row = u >> 5;          // 0..95
    const int c = (u & 31) * 8;
    const int eg = (row < 32) ? (h * 32 + row)
                 : (row < 64) ? (256 + h * 32 + row - 32)
                              : (512 + h * 32 + row - 64);
    *reinterpret_cast<short8*>(&Wq[row * 264 + c]) =
        *reinterpret_cast<const short8*>(&WqkvB[(size_t)eg * 256 + c]);
  }
  float rcp4[4];
#pragma unroll
  for (int r = 0; r < 4; ++r)
    rcp4[r] = 1.0f / denom[b * M + w * 16 + r4 + r];
  __syncthreads();

  // Phase 2: GEMM1 (wave w -> rows w*16..w*16+15, 6 e-tiles)
  floatx4 acc[6] = {{0.f, 0.f, 0.f, 0.f}, {0.f, 0.f, 0.f, 0.f},
                    {0.f, 0.f, 0.f, 0.f}, {0.f, 0.f, 0.f, 0.f},
                    {0.f, 0.f, 0.f, 0.f}, {0.f, 0.f, 0.f, 0.f}};
  const int arow = w * 16 + l15;
#pragma unroll
  for (int ks = 0; ks < 8; ++ks) {
    short8 a = *reinterpret_cast<short8*>(&At[arow * 264 + ks * 32 + q8]);
#pragma unroll
    for (int et = 0; et < 6; ++et) {
      short8 bf = *reinterpret_cast<short8*>(&Wq[(et * 16 + l15) * 264 + ks * 32 + q8]);
      acc[et] = __builtin_amdgcn_mfma_f32_16x16x32_bf16(a, bf, acc[et], 0, 0, 0);
    }
  }
  // preload Wo B-frags for phase 5 (latency hidden under attention)
  short8 wof[4];
#pragma unroll
  for (int dt4 = 0; dt4 < 4; ++dt4)
    wof[dt4] = *reinterpret_cast<const short8*>(
        &WoB[(size_t)(w * 64 + dt4 * 16 + l15) * 256 + h * 32 + q8]);
  __syncthreads();  // all waves done reading At/Wq; overlay region free

  // Phase 3: qkv -> qt/kt/vv (normalized)
#pragma unroll
  for (int r = 0; r < 4; ++r) {
    const int m = w * 16 + r4 + r;
    const float rc = rcp4[r];
#pragma unroll
    for (int et = 0; et < 6; ++et) {
      const float val = acc[et][r] * rc;
      const int c = (et & 1) * 16 + l15;
      if (et < 2) qt[c * 68 + m] = val;
      else if (et < 4) kt[c * 68 + m] = val;
      else vv[m * 36 + c] = val;
    }
  }
  __syncthreads();

  // Phase 4a: S = q.k^T * scale
  {
    const int tm4 = (tid & 15) * 4;
    const int tn4 = (tid >> 4) * 4;
    float sacc[4][4] = {};
    for (int k = 0; k < 32; ++k) {
      float4 a4 = ld4(&qt[k * 68 + tn4]);
      float4 b4 = ld4(&kt[k * 68 + tm4]);
#pragma unroll
      for (int i = 0; i < 4; ++i) {
        const float av = (i == 0) ? a4.x : (i == 1) ? a4.y : (i == 2) ? a4.z : a4.w;
        sacc[i][0] = fmaf(av, b4.x, sacc[i][0]);
        sacc[i][1] = fmaf(av, b4.y, sacc[i][1]);
        sacc[i][2] = fmaf(av, b4.z, sacc[i][2]);
        sacc[i][3] = fmaf(av, b4.w, sacc[i][3]);
      }
    }
    const float scale = 0.17677669529663687f;
#pragma unroll
    for (int i = 0; i < 4; ++i)
      *reinterpret_cast<float4*>(&P[(tn4 + i) * 68 + tm4]) =
          make_float4(sacc[i][0] * scale, sacc[i][1] * scale,
                      sacc[i][2] * scale, sacc[i][3] * scale);
  }
  __syncthreads();
  // Phase 4b: softmax over rows
  if (tid < 64) {
    float mx = -1e30f;
    for (int j = 0; j < 64; ++j) mx = fmaxf(mx, P[tid * 68 + j]);
    float s = 0.0f;
    for (int j = 0; j < 64; ++j) {
      const float e = expf(P[tid * 68 + j] - mx);
      P[tid * 68 + j] = e;
      s += e;
    }
    const float r = 1.0f / s;
    for (int j = 0; j < 64; ++j) P[tid * 68 + j] *= r;
  }
  __syncthreads();
  // Phase 4c: PV -> ao[m][hd]
  if (tid < 128) {
    const int i0 = (tid >> 3) * 4;
    const int c0 = (tid & 7) * 4;
    float o[4][4] = {};
    for (int j = 0; j < 64; ++j) {
      float4 v4 = ld4(&vv[j * 36 + c0]);
#pragma unroll
      for (int ii = 0; ii < 4; ++ii) {
        const float p = P[(i0 + ii) * 68 + j];
        o[ii][0] = fmaf(p, v4.x, o[ii][0]);
        o[ii][1] = fmaf(p, v4.y, o[ii][1]);
        o[ii][2] = fmaf(p, v4.z, o[ii][2]);
        o[ii][3] = fmaf(p, v4.w, o[ii][3]);
      }
    }
#pragma unroll
    for (int ii = 0; ii < 4; ++ii)
#pragma unroll
      for (int jj = 0; jj < 4; ++jj) ao[(i0 + ii) * 36 + c0 + jj] = o[ii][jj];
  }
  __syncthreads();

  // Phase 5: partial out-proj, K=32 (this head's e-slice), wave w -> d-cols w*64..
  floatx4 acc2[4][4] = {{{0.f, 0.f, 0.f, 0.f}, {0.f, 0.f, 0.f, 0.f},
                         {0.f, 0.f, 0.f, 0.f}, {0.f, 0.f, 0.f, 0.f}},
                        {{0.f, 0.f, 0.f, 0.f}, {0.f, 0.f, 0.f, 0.f},
                         {0.f, 0.f, 0.f, 0.f}, {0.f, 0.f, 0.f, 0.f}},
                        {{0.f, 0.f, 0.f, 0.f}, {0.f, 0.f, 0.f, 0.f},
                         {0.f, 0.f, 0.f, 0.f}, {0.f, 0.f, 0.f, 0.f}},
                        {{0.f, 0.f, 0.f, 0.f}, {0.f, 0.f, 0.f, 0.f},
                         {0.f, 0.f, 0.f, 0.f}, {0.f, 0.f, 0.f, 0.f}}};
#pragma unroll
  for (int mt = 0; mt < 4; ++mt) {
    short8 af;
#pragma unroll
    for (int j = 0; j < 8; ++j)
      af[j] = (short)f2bf(ao[(mt * 16 + l15) * 36 + q8 + j]);
#pragma unroll
    for (int dt4 = 0; dt4 < 4; ++dt4)
      acc2[mt][dt4] =
          __builtin_amdgcn_mfma_f32_16x16x32_bf16(af, wof[dt4], acc2[mt][dt4], 0, 0, 0);
  }
#pragma unroll
  for (int mt = 0; mt < 4; ++mt)
#pragma unroll
    for (int dt4 = 0; dt4 < 4; ++dt4)
#pragma unroll
      for (int r = 0; r < 4; ++r) {
        const int m = mt * 16 + r4 + r;
        const int d = w * 64 + dt4 * 16 + l15;
        atomicAdd(&tokO[((size_t)(b * M + m)) * D + d], acc2[mt][dt4][r]);
      }
}

// ---------------------------------------------------------------------------
// K6: out[b,n,d] = sum_m En[b,n,m] * token_out[b,m,d]   (MFMA, K=64)
// Finalize inlined: token_out = (tokO + bo) * rcp(denom) done per block into
// TpS[d-local][m] (redundant per (b,dt) but ~1K cycles). 128-n tiles, 8 waves.
// grid (D/64, N/128, B), block 512
__global__ __launch_bounds__(512, 4) void k6_unpool(
    const unsigned short* __restrict__ En, const float* __restrict__ tokO,
    const float* __restrict__ denom, const float* __restrict__ bo,
    float* __restrict__ out) {
  __shared__ unsigned short EnS[128][72];
  __shared__ unsigned short TpS[64][72];
  const int dt = blockIdx.x, nt = blockIdx.y, b = blockIdx.z;
  const int n0 = nt * 128, d0 = dt * 64;
  const int tid = threadIdx.x;
  const int w = tid >> 6, l = tid & 63;
  const int l15 = l & 15;
  const int q8 = (l >> 4) * 8;
  // stage En rows n0..n0+127
#pragma unroll
  for (int p = 0; p < 2; ++p) {
    const int g = p * 512 + tid;
    const int row = g >> 3;
    const int c8 = (g & 7) * 8;
    *reinterpret_cast<short8*>(&EnS[row][c8]) =
        *reinterpret_cast<const short8*>(
            &En[((size_t)(b * N + n0 + row)) * M + c8]);
  }
  // finalize token_out chunk [64 m][64 d] -> TpS[d-local][m] bf16
  {
    const int m = tid >> 3;
    const int c8 = (tid & 7) * 8;
    const float rc = 1.0f / denom[b * M + m];
    const float* tp = &tokO[((size_t)(b * M + m)) * D + d0 + c8];
    float4 v0 = ld4(tp);
    float4 v1 = ld4(tp + 4);
    float4 bb0 = ld4(&bo[d0 + c8]);
    float4 bb1 = ld4(&bo[d0 + c8 + 4]);
    TpS[c8 + 0][m] = f2bf((v0.x + bb0.x) * rc);
    TpS[c8 + 1][m] = f2bf((v0.y + bb0.y) * rc);
    TpS[c8 + 2][m] = f2bf((v0.z + bb0.z) * rc);
    TpS[c8 + 3][m] = f2bf((v0.w + bb0.w) * rc);
    TpS[c8 + 4][m] = f2bf((v1.x + bb1.x) * rc);
    TpS[c8 + 5][m] = f2bf((v1.y + bb1.y) * rc);
    TpS[c8 + 6][m] = f2bf((v1.z + bb1.z) * rc);
    TpS[c8 + 7][m] = f2bf((v1.w + bb1.w) * rc);
  }
  __syncthreads();
  floatx4 acc[4] = {{0.f, 0.f, 0.f, 0.f},
                    {0.f, 0.f, 0.f, 0.f},
                    {0.f, 0.f, 0.f, 0.f},
                    {0.f, 0.f, 0.f, 0.f}};
  const int arow = w * 16 + l15;
#pragma unroll
  for (int ks = 0; ks < 2; ++ks) {
    short8 a = *reinterpret_cast<short8*>(&EnS[arow][ks * 32 + q8]);
#pragma unroll
    for (int dtile = 0; dtile < 4; ++dtile) {
      short8 bf = *reinterpret_cast<short8*>(
          &TpS[dtile * 16 + l15][ks * 32 + q8]);
      acc[dtile] =
          __builtin_amdgcn_mfma_f32_16x16x32_bf16(a, bf, acc[dtile], 0, 0, 0);
    }
  }
#pragma unroll
  for (int dtile = 0; dtile < 4; ++dtile)
#pragma unroll
    for (int r = 0; r < 4; ++r) {
      const int n = n0 + w * 16 + (l >> 4) * 4 + r;
      const int d = d0 + dtile * 16 + l15;
      out[((size_t)(b * N + n)) * D + d] = acc[dtile][r];
    }
}

// ---------------------------------------------------------------------------
extern "C" void kernel_launch(void* const* d_in, const int* in_sizes, int n_in,
                              void* d_out, int out_size, void* d_ws,
                              size_t ws_size, hipStream_t stream) {
  const float* x = (const float*)d_in[0];
  const float* Ws = (const float*)d_in[1];
  const float* bs = (const float*)d_in[2];
  const float* Wqkv = (const float*)d_in[3];
  const float* Wo = (const float*)d_in[4];
  const float* bo = (const float*)d_in[5];
  float* out = (float*)d_out;

  char* p = (char*)d_ws;
  unsigned short* En = (unsigned short*)p;    p += (size_t)B * N * M * 2;   // 8.4 MB
  float* denom = (float*)p;                   p += (size_t)B * M * 4;
  float* tokens = (float*)p;                  p += (size_t)B * M * D * 4;   // 256 KB
  float* tokO = (float*)p;                    p += (size_t)B * M * D * 4;   // 256 KB
  unsigned short* WsB = (unsigned short*)p;   p += (size_t)M * D * 2;       // 32 KB
  unsigned short* WqkvB = (unsigned short*)p; p += (size_t)3 * D * D * 2;   // 384 KB
  unsigned short* WoB = (unsigned short*)p;   p += (size_t)D * D * 2;       // 128 KB

  k0_prep<<<dim3(136), 256, 0, stream>>>(Ws, Wqkv, Wo, WsB, WqkvB, WoB,
                                         denom, tokens, tokO);
  k1_fused<<<dim3(N / 128, B), 512, 0, stream>>>(x, WsB, bs, En, denom);
  k2_pool<<<dim3(D / 64, N / 256, B), 256, 0, stream>>>(En, x, tokens);
  k_fa<<<dim3(B * H), 256, 0, stream>>>(tokens, WqkvB, WoB, denom, tokO);
  k6_unpool<<<dim3(D / 64, N / 128, B), 512, 0, stream>>>(En, tokO, denom, bo,
                                                          out);
}